// Round 12
// baseline (675.837 us; speedup 1.0000x reference)
//
#include <hip/hip_runtime.h>
#include <hip/hip_bf16.h>
#include <stdint.h>

#define B_   2
#define T_   16
#define D_   128
#define D2_  256
#define H_   64
#define W_   64
#define HW_  4096
#define BT_  32
#define N_   8192
#define ND_  1048576           // N_*D_
#define PLANE_ 16777216        // B*T*D*H*W  (one of re/im)
#define WT_FLOATS 589824       // 256*256*9

typedef short bf16x8 __attribute__((ext_vector_type(8)));
typedef float f32x4 __attribute__((ext_vector_type(4)));
typedef unsigned int uint;
typedef unsigned short ushort;

// ---------------- device helpers ----------------

__device__ __forceinline__ float softplus_f(float x) {
  return fmaxf(x, 0.0f) + log1pf(expf(-fabsf(x)));
}

__device__ __forceinline__ float gelu_fast(float x) {
  const float Ac = 2.3022082963f;   // 2*sqrt(2/pi)*log2(e)
  const float Bc = 0.1029437f;      // Ac*0.044715
  float t = x * x;
  float z = x * fmaf(Bc, t, Ac);
  float e = __builtin_amdgcn_exp2f(z);
  float r = __builtin_amdgcn_rcpf(e + 1.0f);
  return fmaf(-x, r, x);
}

__device__ __forceinline__ float tanh_fast(float x) {
  float e = __builtin_amdgcn_exp2f(x * 2.8853900818f);  // 2*log2(e)
  float r = __builtin_amdgcn_rcpf(e + 1.0f);
  return fmaf(-2.0f, r, 1.0f);
}

__device__ __forceinline__ ushort f2bf(float f) {
  uint u = __float_as_uint(f);
  uint r = (u + 0x7fffu + ((u >> 16) & 1u)) >> 16;   // RNE
  return (ushort)r;
}

__device__ __forceinline__ uint cvt_pk(float a, float b) {
  __hip_bfloat162 h = __float22bfloat162_rn(make_float2(a, b));
  return *reinterpret_cast<uint*>(&h);
}

// ---------------- kernel 1: spatial complex LN + metric -> xri bf16 [BT][H][32u][64w][8ci]
//                  + packed raw residual xp [BT][128][HW] (re,im bf16) ----------------

__global__ __launch_bounds__(256) void k_spatial_ln(
    const float* __restrict__ x_re, const float* __restrict__ x_im,
    const float* __restrict__ g, const float* __restrict__ bb,
    const float* __restrict__ metric, ushort* __restrict__ xri,
    uint* __restrict__ xp) {
  __shared__ float vals[256][64];
  __shared__ float red1[4][64];
  __shared__ float red2[4][64];
  __shared__ float mean_s[64];
  __shared__ float rstd_s[64];
  const int blk = blockIdx.x;      // bt*64 + h
  const int bt = blk >> 6;
  const int h = blk & 63;
  const int tid = threadIdx.x;
  const int w = tid & 63, q = tid >> 6;

  const float* src = (q < 2) ? x_re : x_im;   // wave-uniform
  float s1 = 0.f, s2 = 0.f;
  #pragma unroll 4
  for (int i = 0; i < 64; ++i) {
    const int c = q * 64 + i;
    const int d = c & 127;
    float v = src[((size_t)bt * D_ + d) * HW_ + h * W_ + w];
    vals[c][w] = v;
    s1 += v; s2 += v * v;
  }
  red1[q][w] = s1; red2[q][w] = s2;
  __syncthreads();
  if (tid < 64) {
    float m = red1[0][tid] + red1[1][tid] + red1[2][tid] + red1[3][tid];
    float ss = red2[0][tid] + red2[1][tid] + red2[2][tid] + red2[3][tid];
    m *= (1.f / 256.f);
    float var = ss * (1.f / 256.f) - m * m;
    mean_s[tid] = m;
    rstd_s[tid] = rsqrtf(var + 1e-5f);
  }
  __syncthreads();
  // packed raw residual: all 256 threads, 32 d's each
  #pragma unroll
  for (int i = 0; i < 32; ++i) {
    const int d = q * 32 + i;
    xp[((size_t)bt * D_ + d) * HW_ + h * W_ + w] =
        cvt_pk(vals[d][w], vals[d + 128][w]);
  }
  const float m = mean_s[w], rs = rstd_s[w];
  const size_t ubase = (((size_t)bt * 64 + h) * 32 + q * 8) * 512 + w * 8;
  #pragma unroll
  for (int j = 0; j < 8; ++j) {
    uint4 u;
    #pragma unroll
    for (int e2 = 0; e2 < 4; ++e2) {
      const int c0 = q * 64 + j * 8 + e2 * 2;
      float v0 = (vals[c0][w] - m) * rs * g[c0] + bb[c0];
      v0 *= metric[(size_t)c0 * HW_ + h * W_ + w];
      float v1 = (vals[c0 + 1][w] - m) * rs * g[c0 + 1] + bb[c0 + 1];
      v1 *= metric[(size_t)(c0 + 1) * HW_ + h * W_ + w];
      ((uint*)&u)[e2] = cvt_pk(v0, v1);
    }
    *(uint4*)&xri[ubase + (size_t)j * 512] = u;
  }
}

// ---------------- conv weight prep: fragment-order bf16, tile slots remapped so each wave
// owns re(d) and im(d) of the SAME d. slot nt: cw=nt>>2, jj=nt&3;
// co_tile = (jj<2) ? 2*cw+jj : 8 + 2*cw + (jj-2).

__global__ __launch_bounds__(256) void k_prep_conv(
    const float* __restrict__ wg, ushort* __restrict__ cwswz) {
  const int t = blockIdx.x * 256 + threadIdx.x;   // 0..73727
  if (t >= 73728) return;
  const int lane = t & 63;
  const int nt = (t >> 6) & 15;
  const int ks = (t >> 10) & 7;
  const int kk = t >> 13;                         // 0..8
  const int cwv = nt >> 2, jjv = nt & 3;
  const int co_tile = (jjv < 2) ? (2 * cwv + jjv) : (8 + 2 * cwv + (jjv - 2));
  const int co = co_tile * 16 + (lane & 15);
  const int ci0 = ks * 32 + (lane >> 4) * 8;
  ushort v[8];
  #pragma unroll
  for (int e = 0; e < 8; ++e)
    v[e] = f2bf(wg[((size_t)co * 256 + ci0 + e) * 9 + kk]);
  uint4 u;
  u.x = (uint)v[0] | ((uint)v[1] << 16);
  u.y = (uint)v[2] | ((uint)v[3] << 16);
  u.z = (uint)v[4] | ((uint)v[5] << 16);
  u.w = (uint)v[6] | ((uint)v[7] << 16);
  ((uint4*)cwswz)[t] = u;
}

// ---------------- kernel 2: 3x3 conv via bf16 MFMA -> x2p packed bf16 [BT][128][HW] ----------------
// Quarter-split ci staging: LDS [4 rows][8 units][66 w][8ci] = 33 KB -> 4 blocks/CU
// at VGPR=64 (launch_bounds(512,4): allocator free up to 128, kernel fits in 64).
// Wave-local pack epilogue with packed bf16 residual from xp.

__global__ __launch_bounds__(512, 4) void k_conv_mfma(
    const ushort* __restrict__ xri, const ushort* __restrict__ cwswz,
    const float* __restrict__ bias,
    const uint* __restrict__ xp,
    uint* __restrict__ x2p) {
  __shared__ ushort xb[16896];   // 4 rows * 8 units * 66 w * 8 ci = 33 KB
  const int tid = threadIdx.x;
  const int wave = tid >> 6, lane = tid & 63;
  const int lrow = lane & 15, lgrp = lane >> 4;
  const int blk = blockIdx.x;         // 1024 = bt*32 + hp
  const int bt = blk >> 5;
  const int h0 = (blk & 31) * 2;
  const int cw = wave & 3;
  const int sg = wave >> 2;

  f32x4 acc[4][4];
  #pragma unroll
  for (int j = 0; j < 4; ++j)
    #pragma unroll
    for (int i = 0; i < 4; ++i) acc[j][i] = (f32x4)0.f;

  for (int quarter = 0; quarter < 4; ++quarter) {
    __syncthreads();   // protect previous quarter's reads
    // zero halo (w slots 0 and 65)
    if (tid < 64) {
      const int j = tid >> 4;
      const int u = (tid >> 1) & 7;
      const int wz = (tid & 1) * 65;
      uint4 z = {0u, 0u, 0u, 0u};
      *(uint4*)&xb[((j * 8 + u) * 66 + wz) * 8] = z;
    }
    // coalesced staging: 4 iters x uint4
    #pragma unroll
    for (int i = 0; i < 4; ++i) {
      const int idx = i * 512 + tid;    // 0..2047
      const int w = idx & 63;
      const int u = (idx >> 6) & 7;
      const int j = idx >> 9;           // row 0..3
      const int hh = h0 + j - 1;
      uint4 v = {0u, 0u, 0u, 0u};
      if (hh >= 0 && hh < 64)
        v = *(const uint4*)&xri[(((size_t)bt * 64 + hh) * 32 + quarter * 8 + u) * 512
                                + w * 8];
      *(uint4*)&xb[((j * 8 + u) * 66 + 1 + w) * 8] = v;
    }
    __syncthreads();

    for (int kh = 0; kh < 3; ++kh) {
      for (int kw = 0; kw < 3; ++kw) {
        const int kk = kh * 3 + kw;
        #pragma unroll
        for (int ks = 0; ks < 2; ++ks) {
          bf16x8 bfr[4];
          #pragma unroll
          for (int i = 0; i < 4; ++i)
            bfr[i] = *(const bf16x8*)&xb[(((sg + kh) * 8 + ks * 4 + lgrp) * 66
                                          + i * 16 + lrow + kw) * 8];
          const int fbase = ((kk * 8 + quarter * 2 + ks) * 16 + cw * 4) * 64 + lane;
          #pragma unroll
          for (int j = 0; j < 4; ++j) {
            const bf16x8 afr = ((const bf16x8*)cwswz)[fbase + j * 64];
            #pragma unroll
            for (int i = 0; i < 4; ++i)
              acc[j][i] = __builtin_amdgcn_mfma_f32_16x16x32_bf16(
                  afr, bfr[i], acc[j][i], 0, 0, 0);
          }
        }
      }
    }
  }

  // ---- epilogue: wave-local pack (re = acc[j], im = acc[j+2], same d), bf16 residual
  #pragma unroll
  for (int j = 0; j < 2; ++j) {
    #pragma unroll
    for (int jj = 0; jj < 4; ++jj) {
      const int d = (2 * cw + j) * 16 + lgrp * 4 + jj;   // 0..127
      const float bvr = bias[d];
      const float bvi = bias[d + 128];
      const size_t rowoff = ((size_t)bt * D_ + d) * HW_ + (h0 + sg) * W_;
      #pragma unroll
      for (int i = 0; i < 4; ++i) {
        const int w = i * 16 + lrow;
        const uint xv = xp[rowoff + w];
        const float re = acc[j][i][jj] + bvr + __uint_as_float(xv << 16);
        const float im = acc[j + 2][i][jj] + bvi + __uint_as_float(xv & 0xffff0000u);
        x2p[rowoff + w] = cvt_pk(re, im);
      }
    }
  }
}

// ---------------- decay/forcing table ----------------

__global__ __launch_bounds__(256) void k_prep_decay(
    const float* __restrict__ dt, const float* __restrict__ nu,
    const float* __restrict__ theta, float4* __restrict__ decay) {
  const int idx = blockIdx.x * 256 + threadIdx.x;  // 0..4095
  const int d = idx & 127;
  const int bt = idx >> 7;
  const float dtv = dt[bt];
  const float lr = -softplus_f(nu[d]);
  const float li = theta[d];
  float s, c;
  sincosf(li * dtv, &s, &c);
  const float er = expf(lr * dtv);
  const float ar = er * c, ai = er * s;
  const float den = lr * lr + li * li;
  const float nr = ar - 1.f, ni = ai;
  float4 v;
  v.x = ar; v.y = ai;
  v.z = (nr * lr + ni * li) / den;
  v.w = (ni * lr - nr * li) / den;
  decay[idx] = v;
}

// ---------------- temporal-encode weight prep ----------------

__global__ __launch_bounds__(256) void k_prep_enc(
    const float* __restrict__ enc_re, const float* __restrict__ enc_im,
    const float* __restrict__ g, ushort* __restrict__ encswz) {
  const int t = blockIdx.x * 256 + threadIdx.x;   // 0..8191
  const int lane = t & 63;
  const int ks = (t >> 6) & 7;
  const int ntile = t >> 9;
  const int n = ntile * 16 + (lane & 15);
  const int k0 = ks * 32 + (lane >> 4) * 8;
  ushort v[8];
  #pragma unroll
  for (int e = 0; e < 8; ++e) {
    const int kp = k0 + e;
    const int k = (kp >> 1) | ((kp & 1) << 7);   // physical -> logical
    float val;
    if (k < 128) {
      val = (n < 128) ? enc_re[k * 128 + n] : enc_im[k * 128 + (n - 128)];
    } else {
      const int kk = k - 128;
      val = (n < 128) ? -enc_im[kk * 128 + n] : enc_re[kk * 128 + (n - 128)];
    }
    v[e] = f2bf(val * g[k]);
  }
  uint4 u;
  u.x = (uint)v[0] | ((uint)v[1] << 16);
  u.y = (uint)v[2] | ((uint)v[3] << 16);
  u.z = (uint)v[4] | ((uint)v[5] << 16);
  u.w = (uint)v[6] | ((uint)v[7] << 16);
  ((uint4*)encswz)[t] = u;
}

__global__ __launch_bounds__(256) void k_prep_encvec(
    const float* __restrict__ enc_re, const float* __restrict__ enc_im,
    const float* __restrict__ g, const float* __restrict__ bb,
    float* __restrict__ evec, float* __restrict__ cvec) {
  const int n = threadIdx.x;   // one block of 256
  float se = 0.f, sc = 0.f;
  for (int k = 0; k < 256; ++k) {
    float ep;
    if (k < 128) {
      ep = (n < 128) ? enc_re[k * 128 + n] : enc_im[k * 128 + (n - 128)];
    } else {
      const int kk = k - 128;
      ep = (n < 128) ? -enc_im[kk * 128 + n] : enc_re[kk * 128 + (n - 128)];
    }
    se = fmaf(g[k], ep, se);
    sc = fmaf(bb[k], ep, sc);
  }
  evec[n] = se;
  cvec[n] = sc;
}

__global__ __launch_bounds__(256) void k_prep_dec(
    const float* __restrict__ dec_re, const float* __restrict__ dec_im,
    ushort* __restrict__ decswz) {
  const int t = blockIdx.x * 256 + threadIdx.x;   // 0..4095
  const int lane = t & 63;
  const int ks = (t >> 6) & 7;
  const int ntile = t >> 9;
  const int n = ntile * 16 + (lane & 15);
  const int k0 = ks * 32 + (lane >> 4) * 8;
  ushort v[8];
  #pragma unroll
  for (int e = 0; e < 8; ++e) {
    const int kp = k0 + e;
    const int k = (kp >> 1) | ((kp & 1) << 7);
    float val = (k < 128) ? dec_re[k * 128 + n] : -dec_im[(k - 128) * 128 + n];
    v[e] = f2bf(val);
  }
  uint4 u;
  u.x = (uint)v[0] | ((uint)v[1] << 16);
  u.y = (uint)v[2] | ((uint)v[3] << 16);
  u.z = (uint)v[4] | ((uint)v[5] << 16);
  u.w = (uint)v[6] | ((uint)v[7] << 16);
  ((uint4*)decswz)[t] = u;
}

// ---------------- kernel 3: temporal LN (folded) + encode MFMA + src + ZOH -> u32 [T][D][N] ----------------

__global__ __launch_bounds__(256, 2) void k_temporal_mfma(
    const uint* __restrict__ x2p,
    const ushort* __restrict__ encswz,
    const float* __restrict__ evec, const float* __restrict__ cvec,
    const float4* __restrict__ decay,
    const float* __restrict__ src_gain,
    uint* __restrict__ u32) {
  __shared__ ushort xlds[64][256];
  __shared__ float red1[4][64], red2[4][64];
  __shared__ float mean_s[64], rstd_s[64];
  __shared__ float fre_s[128], fim_s[128], gain_s[128];
  const int tid = threadIdx.x;
  const int wave = tid >> 6, lane = tid & 63;
  const int lrow = lane & 15, lgrp = lane >> 4;
  const int blk = blockIdx.x;          // ((b*16)+t)*64 + h
  const int h = blk & 63;
  const int t = (blk >> 6) & 15;
  const int b = blk >> 10;
  const int bt = b * T_ + t;

  // stage packed x2 -> LDS (pass-through) + LN sums
  float s1 = 0.f, s2 = 0.f;
  #pragma unroll
  for (int i = 0; i < 8; ++i) {
    const int q = i * 4 + wave;        // d-quad 0..31
    const uint* src = &x2p[((size_t)bt * D_ + q * 4) * HW_ + h * W_ + lane];
    uint4 u;
    u.x = src[0];
    u.y = src[HW_];
    u.z = src[2 * HW_];
    u.w = src[3 * HW_];
    *(uint4*)&xlds[lane][(q ^ (lane & 7)) << 3] = u;
    #pragma unroll
    for (int e = 0; e < 4; ++e) {
      const uint v = ((const uint*)&u)[e];
      const float re = __uint_as_float(v << 16);
      const float im = __uint_as_float(v & 0xffff0000u);
      s1 += re + im;
      s2 += re * re + im * im;
    }
  }
  red1[wave][lane] = s1;
  red2[wave][lane] = s2;
  __syncthreads();
  if (tid < 64) {
    float m = red1[0][tid] + red1[1][tid] + red1[2][tid] + red1[3][tid];
    float ss = red2[0][tid] + red2[1][tid] + red2[2][tid] + red2[3][tid];
    m *= (1.f / 256.f);
    float var = ss * (1.f / 256.f) - m * m;
    mean_s[tid] = m;
    rstd_s[tid] = rsqrtf(var + 1e-5f);
  }
  if (tid < 128) {
    const float4 dc = decay[bt * 128 + tid];
    fre_s[tid] = dc.z;
    fim_s[tid] = dc.w;
    gain_s[tid] = src_gain[tid];
  }
  __syncthreads();

  f32x4 acc[4][4];
  #pragma unroll
  for (int ntl = 0; ntl < 4; ++ntl)
    #pragma unroll
    for (int st = 0; st < 4; ++st) acc[ntl][st] = (f32x4)0.f;

  const int swz = lrow & 7;
  const int ntb[4] = {wave * 2, wave * 2 + 1, wave * 2 + 8, wave * 2 + 9};
  #pragma unroll
  for (int ks = 0; ks < 8; ++ks) {
    bf16x8 bfr[4];
    #pragma unroll
    for (int st = 0; st < 4; ++st)
      bfr[st] = *(const bf16x8*)&xlds[st * 16 + lrow][(((ks * 4 + lgrp) ^ swz)) << 3];
    #pragma unroll
    for (int ntl = 0; ntl < 4; ++ntl) {
      const bf16x8 afr = ((const bf16x8*)encswz)[(ntb[ntl] * 8 + ks) * 64 + lane];
      #pragma unroll
      for (int st = 0; st < 4; ++st)
        acc[ntl][st] = __builtin_amdgcn_mfma_f32_16x16x32_bf16(
            afr, bfr[st], acc[ntl][st], 0, 0, 0);
    }
  }

  const int nbase = (b * 64 + h) * 64;
  #pragma unroll
  for (int ntl = 0; ntl < 2; ++ntl) {
    const int d0 = ntb[ntl] * 16 + lgrp * 4;    // <128
    #pragma unroll
    for (int st = 0; st < 4; ++st) {
      const int site = st * 16 + lrow;
      const float m = mean_s[site], rs = rstd_s[site];
      #pragma unroll
      for (int j = 0; j < 4; ++j) {
        const int d = d0 + j;
        const float xer = rs * acc[ntl][st][j] - rs * m * evec[d] + cvec[d];
        const float xei = rs * acc[ntl + 2][st][j] - rs * m * evec[d + 128] + cvec[d + 128];
        const float sr = tanh_fast(xer) * gain_s[d];
        const float si = tanh_fast(xei) * gain_s[d];
        const float vr = xer + sr, vi = xei + si;
        const float ur = vr * fre_s[d] - vi * fim_s[d];
        const float ui = vr * fim_s[d] + vi * fre_s[d];
        u32[(size_t)t * ND_ + (size_t)d * N_ + nbase + site] = cvt_pk(ur, ui);
      }
    }
  }
}

// ---------------- kernel 4: sequential scan over T (in place, packed bf16 u32 [T][D][N]) ----------------

__global__ __launch_bounds__(256) void k_scan(
    uint* __restrict__ u32, const float4* __restrict__ decay) {
  const int idx = blockIdx.x * 256 + threadIdx.x;   // d*N + n
  const int n = idx & 8191;
  const int d = idx >> 13;
  const int b = n >> 12;
  float hr = 0.f, hi = 0.f;
  #pragma unroll
  for (int t = 0; t < 16; ++t) {
    const float4 dc = decay[(b * 16 + t) * 128 + d];   // wave-uniform
    const size_t off = (size_t)t * ND_ + idx;
    const uint v = u32[off];
    const float ur = __uint_as_float(v << 16);
    const float ui = __uint_as_float(v & 0xffff0000u);
    const float nr = fmaf(dc.x, hr, fmaf(-dc.y, hi, ur));
    const float ni = fmaf(dc.x, hi, fmaf(dc.y, hr, ui));
    hr = nr; hi = ni;
    u32[off] = cvt_pk(hr, hi);
  }
}

// ---------------- FFN weight prep ----------------

__global__ __launch_bounds__(256) void k_prep_b1(
    const float* __restrict__ w1_re, const float* __restrict__ w1_im,
    ushort* __restrict__ b1swz) {
  const int t = blockIdx.x * 256 + threadIdx.x;   // 0..32767
  const int lane = t & 63;
  const int ks = (t >> 6) & 7;
  const int ntile = t >> 9;
  const int n = ntile * 16 + (lane & 15);
  const int k0 = ks * 32 + (lane >> 4) * 8;
  ushort v[8];
  #pragma unroll
  for (int e = 0; e < 8; ++e) {
    const int kp = k0 + e;
    const int k = (kp >> 1) | ((kp & 1) << 7);   // physical -> logical
    float val;
    if (k < 128) {
      val = (n < 512) ? w1_re[k * 512 + n] : w1_im[k * 512 + (n - 512)];
    } else {
      const int kk = k - 128;
      val = (n < 512) ? -w1_im[kk * 512 + n] : w1_re[kk * 512 + (n - 512)];
    }
    v[e] = f2bf(val);
  }
  uint4 u;
  u.x = (uint)v[0] | ((uint)v[1] << 16);
  u.y = (uint)v[2] | ((uint)v[3] << 16);
  u.z = (uint)v[4] | ((uint)v[5] << 16);
  u.w = (uint)v[6] | ((uint)v[7] << 16);
  ((uint4*)b1swz)[t] = u;
}

__global__ __launch_bounds__(256) void k_prep_b2(
    const float* __restrict__ w2_re, const float* __restrict__ w2_im,
    ushort* __restrict__ b2swz) {
  const int t = blockIdx.x * 256 + threadIdx.x;   // 0..32767
  const int lane = t & 63;
  const int kc = (t >> 6) & 31;
  const int rowtile = t >> 11;
  const int n2 = rowtile * 16 + (lane & 15);
  const int k0 = kc * 32 + (lane >> 4) * 8;
  ushort v[8];
  #pragma unroll
  for (int e = 0; e < 8; ++e) {
    const int k = k0 + e;                       // act layout: no permute
    float val;
    if (k < 512) {
      val = (n2 < 128) ? w2_re[k * 128 + n2] : w2_im[k * 128 + (n2 - 128)];
    } else {
      const int kk = k - 512;
      val = (n2 < 128) ? -w2_im[kk * 128 + n2] : w2_re[kk * 128 + (n2 - 128)];
    }
    v[e] = f2bf(val);
  }
  uint4 u;
  u.x = (uint)v[0] | ((uint)v[1] << 16);
  u.y = (uint)v[2] | ((uint)v[3] << 16);
  u.z = (uint)v[4] | ((uint)v[5] << 16);
  u.w = (uint)v[6] | ((uint)v[7] << 16);
  ((uint4*)b2swz)[t] = u;
}

// ---------------- kernel 6: drift-decode (fused) + complex FFN via bf16 MFMA ----------------

__global__ __launch_bounds__(256, 2) void k_ffn_mfma(
    const uint* __restrict__ x2p, const uint* __restrict__ h32,
    const ushort* __restrict__ decswz,
    const ushort* __restrict__ b1swz, const ushort* __restrict__ b2swz,
    const float* __restrict__ b1_re, const float* __restrict__ b1_im,
    const float* __restrict__ b2_re, const float* __restrict__ b2_im,
    float* __restrict__ out) {
  __shared__ ushort xlds[64][256];
  __shared__ ushort actlds[2][64][136];
  const int tid = threadIdx.x;
  const int wave = tid >> 6, lane = tid & 63;
  const int lrow = lane & 15, lgrp = lane >> 4;
  const int blk = blockIdx.x;        // 2048 = bt*64 + h
  const int bt = blk >> 6;
  const int hrow = blk & 63;
  const int hw0 = hrow * 64;
  const int b = bt >> 4, t = bt & 15;
  const int nbase = (b * 64 + hrow) * 64;
  const bf16x8* b1f = (const bf16x8*)b1swz;
  const bf16x8* b2f = (const bf16x8*)b2swz;
  const bf16x8* dcf = (const bf16x8*)decswz;
  ushort* hbuf = &actlds[0][0][0];   // [64 site][264 pad] view, dead before chunk 0

  // stage x2 (packed, pass-through) and h (packed)
  #pragma unroll
  for (int i = 0; i < 8; ++i) {
    const int q = i * 4 + wave;        // d-quad 0..31
    const uint* src = &x2p[((size_t)bt * D_ + q * 4) * HW_ + hw0 + lane];
    uint4 u;
    u.x = src[0]; u.y = src[HW_]; u.z = src[2 * HW_]; u.w = src[3 * HW_];
    *(uint4*)&xlds[lane][(q ^ (lane & 7)) << 3] = u;
  }
  #pragma unroll
  for (int i = 0; i < 8; ++i) {
    const int q = i * 4 + wave;
    const size_t o = (size_t)t * ND_ + (size_t)(q * 4) * N_ + nbase + lane;
    uint4 u;
    u.x = h32[o]; u.y = h32[o + N_]; u.z = h32[o + 2 * N_]; u.w = h32[o + 3 * N_];
    *(uint4*)&hbuf[lane * 264 + ((q ^ (lane & 7)) << 3)] = u;
  }

  // prefetch chunk-0 A-fragments
  bf16x8 a1[2][8];
  #pragma unroll
  for (int ntl = 0; ntl < 2; ++ntl)
    #pragma unroll
    for (int ks = 0; ks < 8; ++ks)
      a1[ntl][ks] = b1f[((wave * 2 + ntl) * 8 + ks) * 64 + lane];
  bf16x8 a2[4][2];
  #pragma unroll
  for (int rt = 0; rt < 4; ++rt)
    #pragma unroll
    for (int k2 = 0; k2 < 2; ++k2)
      a2[rt][k2] = b2f[((wave * 4 + rt) * 32 + k2) * 64 + lane];

  __syncthreads();
  const int swz = lrow & 7;

  // ---- fused decode: drift = h @ decP (real), RMW into xlds re-halves
  {
    f32x4 dr[2][4];
    #pragma unroll
    for (int ntl = 0; ntl < 2; ++ntl)
      #pragma unroll
      for (int st = 0; st < 4; ++st) dr[ntl][st] = (f32x4)0.f;
    #pragma unroll
    for (int ks = 0; ks < 8; ++ks) {
      bf16x8 bfr[4];
      #pragma unroll
      for (int st = 0; st < 4; ++st)
        bfr[st] = *(const bf16x8*)&hbuf[(st * 16 + lrow) * 264
                                        + (((ks * 4 + lgrp) ^ swz) << 3)];
      #pragma unroll
      for (int ntl = 0; ntl < 2; ++ntl) {
        const bf16x8 afr = dcf[((wave * 2 + ntl) * 8 + ks) * 64 + lane];
        #pragma unroll
        for (int st = 0; st < 4; ++st)
          dr[ntl][st] = __builtin_amdgcn_mfma_f32_16x16x32_bf16(
              afr, bfr[st], dr[ntl][st], 0, 0, 0);
      }
    }
    #pragma unroll
    for (int ntl = 0; ntl < 2; ++ntl) {
      #pragma unroll
      for (int st = 0; st < 4; ++st) {
        const int site = st * 16 + lrow;
        #pragma unroll
        for (int j = 0; j < 4; ++j) {
          const int d = (wave * 2 + ntl) * 16 + lgrp * 4 + j;
          ushort* p = &xlds[site][(((d >> 2) ^ (site & 7)) << 3) + (d & 3) * 2];
          const uint v = *(uint*)p;
          const float re = __uint_as_float(v << 16) + dr[ntl][st][j];
          *(uint*)p = (v & 0xffff0000u) | (uint)f2bf(re);
        }
      }
    }
  }
  __syncthreads();   // xlds now holds x3; hbuf (actlds) free

  f32x4 dacc[4][4];
  #pragma unroll
  for (int rt = 0; rt < 4; ++rt)
    #pragma unroll
    for (int st = 0; st < 4; ++st) dacc[rt][st] = (f32x4)0.f;

  for (int chunk = 0; chunk < 8; ++chunk) {
    const int nc = (chunk + 1) & 7;

    // ---- GEMM1(chunk)
    f32x4 hacc[2][4];
    #pragma unroll
    for (int ntl = 0; ntl < 2; ++ntl)
      #pragma unroll
      for (int st = 0; st < 4; ++st) hacc[ntl][st] = (f32x4)0.f;

    #pragma unroll
    for (int ks = 0; ks < 8; ++ks) {
      bf16x8 bfr[4];
      #pragma unroll
      for (int st = 0; st < 4; ++st)
        bfr[st] = *(const bf16x8*)&xlds[st * 16 + lrow][(((ks * 4 + lgrp) ^ swz)) << 3];
      #pragma unroll
      for (int ntl = 0; ntl < 2; ++ntl)
        #pragma unroll
        for (int st = 0; st < 4; ++st)
          hacc[ntl][st] = __builtin_amdgcn_mfma_f32_16x16x32_bf16(
              a1[ntl][ks], bfr[st], hacc[ntl][st], 0, 0, 0);
    }

    // ---- prefetch a1 for next chunk
    #pragma unroll
    for (int ntl = 0; ntl < 2; ++ntl)
      #pragma unroll
      for (int ks = 0; ks < 8; ++ks)
        a1[ntl][ks] = b1f[((nc * 8 + wave * 2 + ntl) * 8 + ks) * 64 + lane];

    // ---- bias + gelu -> act[chunk&1]
    uint* act32 = (uint*)&actlds[chunk & 1][0][0];
    #pragma unroll
    for (int ntl = 0; ntl < 2; ++ntl) {
      const int nlocal0 = (wave * 2 + ntl) * 16 + lgrp * 4;
      const int ng0 = chunk * 128 + nlocal0;
      #pragma unroll
      for (int st = 0; st < 4; ++st) {
        float gv[4];
        #pragma unroll
        for (int j = 0; j < 4; ++j) {
          const int ng = ng0 + j;
          const float bias = (ng < 512) ? b1_re[ng] : b1_im[ng - 512];
          gv[j] = gelu_fast(hacc[ntl][st][j] + bias);
        }
        const int site = st * 16 + lrow;
        act32[site * 68 + (nlocal0 >> 1)] = cvt_pk(gv[0], gv[1]);
        act32[site * 68 + (nlocal0 >> 1) + 1] = cvt_pk(gv[2], gv[3]);
      }
    }

    // ---- load this chunk's GEMM2 ks2 2-3 frags
    bf16x8 a2b[4][2];
    #pragma unroll
    for (int rt = 0; rt < 4; ++rt)
      #pragma unroll
      for (int k2 = 0; k2 < 2; ++k2)
        a2b[rt][k2] = b2f[((wave * 4 + rt) * 32 + chunk * 4 + 2 + k2) * 64 + lane];

    __syncthreads();   // act[chunk&1] ready (one barrier/chunk)

    // ---- GEMM2(chunk)
    const ushort* actb = &actlds[chunk & 1][0][0];
    #pragma unroll
    for (int ks2 = 0; ks2 < 2; ++ks2) {
      bf16x8 bfr[4];
      #pragma unroll
      for (int st = 0; st < 4; ++st)
        bfr[st] = *(const bf16x8*)&actb[(st * 16 + lrow) * 136 + ks2 * 32 + lgrp * 8];
      #pragma unroll
      for (int rt = 0; rt < 4; ++rt)
        #pragma unroll
        for (int st = 0; st < 4; ++st)
          dacc[rt][st] = __builtin_amdgcn_mfma_f32_16x16x32_bf16(
              a2[rt][ks2], bfr[st], dacc[rt][st], 0, 0, 0);
    }
    #pragma unroll
    for (int ks2 = 0; ks2 < 2; ++ks2) {
      bf16x8 bfr[4];
      #pragma unroll
      for (int st = 0; st < 4; ++st)
        bfr[st] = *(const bf16x8*)&actb[(st * 16 + lrow) * 136 + (ks2 + 2) * 32 + lgrp * 8];
      #pragma unroll
      for (int rt = 0; rt < 4; ++rt)
        #pragma unroll
        for (int st = 0; st < 4; ++st)
          dacc[rt][st] = __builtin_amdgcn_mfma_f32_16x16x32_bf16(
              a2b[rt][ks2], bfr[st], dacc[rt][st], 0, 0, 0);
    }

    // ---- prefetch next chunk's GEMM2 ks2 0-1 frags
    #pragma unroll
    for (int rt = 0; rt < 4; ++rt)
      #pragma unroll
      for (int k2 = 0; k2 < 2; ++k2)
        a2[rt][k2] = b2f[((wave * 4 + rt) * 32 + nc * 4 + k2) * 64 + lane];
  }

  // epilogue: residual x3 from xlds, bias2, interleaved [.,2] output
  #pragma unroll
  for (int rt = 0; rt < 4; ++rt) {
    #pragma unroll
    for (int j = 0; j < 4; ++j) {
      const int n2 = (wave * 4 + rt) * 16 + lgrp * 4 + j;
      const int d = n2 & 127;
      const int c = n2 >> 7;
      const float bias2 = c ? b2_im[d] : b2_re[d];
      #pragma unroll
      for (int st = 0; st < 4; ++st) {
        const int site = st * 16 + lrow;
        const uint pr = *(const uint*)&xlds[site][(((d >> 2) ^ (site & 7)) << 3)
                                                  + (d & 3) * 2];
        const float rv = c ? __uint_as_float(pr & 0xffff0000u)
                           : __uint_as_float(pr << 16);
        const size_t idx = (size_t)(bt * D_ + d) * HW_ + hw0 + site;
        out[idx * 2 + c] = rv + dacc[rt][st][j] + bias2;
      }
    }
  }
}

// ---------------- host launcher ----------------

extern "C" void kernel_launch(void* const* d_in, const int* in_sizes, int n_in,
                              void* d_out, int out_size, void* d_ws, size_t ws_size,
                              hipStream_t stream) {
  const float* x_re   = (const float*)d_in[0];
  const float* x_im   = (const float*)d_in[1];
  const float* dt     = (const float*)d_in[2];
  const float* ln_s_g = (const float*)d_in[3];
  const float* ln_s_b = (const float*)d_in[4];
  const float* ln_t_g = (const float*)d_in[5];
  const float* ln_t_b = (const float*)d_in[6];
  const float* metric = (const float*)d_in[7];
  const float* conv_w = (const float*)d_in[8];
  const float* conv_b = (const float*)d_in[9];
  const float* nu     = (const float*)d_in[10];
  const float* theta  = (const float*)d_in[11];
  const float* enc_re = (const float*)d_in[12];
  const float* enc_im = (const float*)d_in[13];
  const float* dec_re = (const float*)d_in[14];
  const float* dec_im = (const float*)d_in[15];
  const float* src_g  = (const float*)d_in[16];
  const float* w1_re  = (const float*)d_in[17];
  const float* w1_im  = (const float*)d_in[18];
  const float* b1_re  = (const float*)d_in[19];
  const float* b1_im  = (const float*)d_in[20];
  const float* w2_re  = (const float*)d_in[21];
  const float* w2_im  = (const float*)d_in[22];
  const float* b2_re  = (const float*)d_in[23];
  const float* b2_im  = (const float*)d_in[24];
  float* out = (float*)d_out;
  float* ws = (float*)d_ws;

  // workspace layout
  float* wt   = ws;                          // weight-prep region (~2.5 MB)
  float* bufA = ws + WT_FLOATS;
  ushort* wt16  = (ushort*)wt;
  ushort* cwswz = wt16;                      // conv frags (dead after conv)
  ushort* b1swz = wt16;                      // FFN frags (overwrite after conv)
  ushort* b2swz = wt16 + 262144;
  ushort* encswz = wt16 + 524288;
  ushort* decswz = wt16 + 589824;
  float*  evec   = (float*)(wt16 + 622592);
  float*  cvec   = evec + 256;
  float4* decay  = (float4*)(cvec + 256);    // 64 KB
  ushort* xri_bf = (ushort*)bufA;            // 67 MB (dead after conv)

  // planA: xri | u32(+128KB skew over xri) | x2p(+256KB skew) | xp(+512KB skew)
  const size_t needA = ((size_t)WT_FLOATS + 3 * (size_t)PLANE_) * 4 + (2u << 20);
  const bool planA = ws_size >= needA;
  uint *u32p, *x2p, *xp;
  float* ffn_out;
  if (planA) {
    u32p = (uint*)bufA + 32768;                      // overwrites dead xri (skewed)
    x2p  = (uint*)bufA + PLANE_ + 65536;
    xp   = (uint*)bufA + 2 * (size_t)PLANE_ + 131072;
    ffn_out = out;
  } else {
    // route u32/x2p through d_out; xp in ws after xri; final d2d copy
    u32p = (uint*)out;
    x2p  = (uint*)out + PLANE_;
    xp   = (uint*)bufA + PLANE_;
    ffn_out = bufA;
  }

  k_prep_conv<<<288, 256, 0, stream>>>(conv_w, cwswz);
  k_prep_decay<<<16, 256, 0, stream>>>(dt, nu, theta, decay);
  k_spatial_ln<<<BT_ * H_, 256, 0, stream>>>(x_re, x_im, ln_s_g, ln_s_b, metric,
                                             xri_bf, xp);
  k_conv_mfma<<<BT_ * 32, 512, 0, stream>>>(xri_bf, cwswz, conv_b, xp, x2p);
  // cwswz dead after conv; overwrite region with GEMM weights
  k_prep_b1<<<128, 256, 0, stream>>>(w1_re, w1_im, b1swz);
  k_prep_b2<<<128, 256, 0, stream>>>(w2_re, w2_im, b2swz);
  k_prep_enc<<<32, 256, 0, stream>>>(enc_re, enc_im, ln_t_g, encswz);
  k_prep_encvec<<<1, 256, 0, stream>>>(enc_re, enc_im, ln_t_g, ln_t_b, evec, cvec);
  k_prep_dec<<<16, 256, 0, stream>>>(dec_re, dec_im, decswz);
  k_temporal_mfma<<<B_ * T_ * H_, 256, 0, stream>>>(x2p, encswz, evec, cvec,
                                                    decay, src_g, u32p);
  k_scan<<<ND_ / 256, 256, 0, stream>>>(u32p, decay);
  k_ffn_mfma<<<BT_ * H_, 256, 0, stream>>>(x2p, u32p, decswz, b1swz, b2swz,
                                           b1_re, b1_im, b2_re, b2_im, ffn_out);
  if (!planA) {
    hipMemcpyAsync(d_out, ffn_out, (size_t)2 * PLANE_ * sizeof(float),
                   hipMemcpyDeviceToDevice, stream);
  }
}

// Round 13
// 665.454 us; speedup vs baseline: 1.0156x; 1.0156x over previous
//
#include <hip/hip_runtime.h>
#include <hip/hip_bf16.h>
#include <stdint.h>

#define B_   2
#define T_   16
#define D_   128
#define D2_  256
#define H_   64
#define W_   64
#define HW_  4096
#define BT_  32
#define N_   8192
#define ND_  1048576           // N_*D_
#define PLANE_ 16777216        // B*T*D*H*W  (one of re/im)
#define WT_FLOATS 589824       // 256*256*9

typedef short bf16x8 __attribute__((ext_vector_type(8)));
typedef float f32x4 __attribute__((ext_vector_type(4)));
typedef unsigned int uint;
typedef unsigned short ushort;

// ---------------- device helpers ----------------

__device__ __forceinline__ float softplus_f(float x) {
  return fmaxf(x, 0.0f) + log1pf(expf(-fabsf(x)));
}

__device__ __forceinline__ float gelu_fast(float x) {
  const float Ac = 2.3022082963f;   // 2*sqrt(2/pi)*log2(e)
  const float Bc = 0.1029437f;      // Ac*0.044715
  float t = x * x;
  float z = x * fmaf(Bc, t, Ac);
  float e = __builtin_amdgcn_exp2f(z);
  float r = __builtin_amdgcn_rcpf(e + 1.0f);
  return fmaf(-x, r, x);
}

__device__ __forceinline__ float tanh_fast(float x) {
  float e = __builtin_amdgcn_exp2f(x * 2.8853900818f);  // 2*log2(e)
  float r = __builtin_amdgcn_rcpf(e + 1.0f);
  return fmaf(-2.0f, r, 1.0f);
}

__device__ __forceinline__ ushort f2bf(float f) {
  uint u = __float_as_uint(f);
  uint r = (u + 0x7fffu + ((u >> 16) & 1u)) >> 16;   // RNE
  return (ushort)r;
}

__device__ __forceinline__ uint cvt_pk(float a, float b) {
  __hip_bfloat162 h = __float22bfloat162_rn(make_float2(a, b));
  return *reinterpret_cast<uint*>(&h);
}

// ---------------- kernel 1: spatial complex LN + metric -> xri bf16 [BT][H][32u][64w][8ci]
//                  + packed raw residual xp [BT][128][HW] (re,im bf16) ----------------

__global__ __launch_bounds__(256) void k_spatial_ln(
    const float* __restrict__ x_re, const float* __restrict__ x_im,
    const float* __restrict__ g, const float* __restrict__ bb,
    const float* __restrict__ metric, ushort* __restrict__ xri,
    uint* __restrict__ xp) {
  __shared__ float vals[256][64];
  __shared__ float red1[4][64];
  __shared__ float red2[4][64];
  __shared__ float mean_s[64];
  __shared__ float rstd_s[64];
  const int blk = blockIdx.x;      // bt*64 + h
  const int bt = blk >> 6;
  const int h = blk & 63;
  const int tid = threadIdx.x;
  const int w = tid & 63, q = tid >> 6;

  const float* src = (q < 2) ? x_re : x_im;   // wave-uniform
  float s1 = 0.f, s2 = 0.f;
  #pragma unroll 4
  for (int i = 0; i < 64; ++i) {
    const int c = q * 64 + i;
    const int d = c & 127;
    float v = src[((size_t)bt * D_ + d) * HW_ + h * W_ + w];
    vals[c][w] = v;
    s1 += v; s2 += v * v;
  }
  red1[q][w] = s1; red2[q][w] = s2;
  __syncthreads();
  if (tid < 64) {
    float m = red1[0][tid] + red1[1][tid] + red1[2][tid] + red1[3][tid];
    float ss = red2[0][tid] + red2[1][tid] + red2[2][tid] + red2[3][tid];
    m *= (1.f / 256.f);
    float var = ss * (1.f / 256.f) - m * m;
    mean_s[tid] = m;
    rstd_s[tid] = rsqrtf(var + 1e-5f);
  }
  __syncthreads();
  // packed raw residual: all 256 threads, 32 d's each
  #pragma unroll
  for (int i = 0; i < 32; ++i) {
    const int d = q * 32 + i;
    xp[((size_t)bt * D_ + d) * HW_ + h * W_ + w] =
        cvt_pk(vals[d][w], vals[d + 128][w]);
  }
  const float m = mean_s[w], rs = rstd_s[w];
  const size_t ubase = (((size_t)bt * 64 + h) * 32 + q * 8) * 512 + w * 8;
  #pragma unroll
  for (int j = 0; j < 8; ++j) {
    uint4 u;
    #pragma unroll
    for (int e2 = 0; e2 < 4; ++e2) {
      const int c0 = q * 64 + j * 8 + e2 * 2;
      float v0 = (vals[c0][w] - m) * rs * g[c0] + bb[c0];
      v0 *= metric[(size_t)c0 * HW_ + h * W_ + w];
      float v1 = (vals[c0 + 1][w] - m) * rs * g[c0 + 1] + bb[c0 + 1];
      v1 *= metric[(size_t)(c0 + 1) * HW_ + h * W_ + w];
      ((uint*)&u)[e2] = cvt_pk(v0, v1);
    }
    *(uint4*)&xri[ubase + (size_t)j * 512] = u;
  }
}

// ---------------- conv weight prep: fragment-order bf16, tile slots remapped so each wave
// owns re(d) and im(d) of the SAME d. slot nt: cw=nt>>2, jj=nt&3;
// co_tile = (jj<2) ? 2*cw+jj : 8 + 2*cw + (jj-2).

__global__ __launch_bounds__(256) void k_prep_conv(
    const float* __restrict__ wg, ushort* __restrict__ cwswz) {
  const int t = blockIdx.x * 256 + threadIdx.x;   // 0..73727
  if (t >= 73728) return;
  const int lane = t & 63;
  const int nt = (t >> 6) & 15;
  const int ks = (t >> 10) & 7;
  const int kk = t >> 13;                         // 0..8
  const int cwv = nt >> 2, jjv = nt & 3;
  const int co_tile = (jjv < 2) ? (2 * cwv + jjv) : (8 + 2 * cwv + (jjv - 2));
  const int co = co_tile * 16 + (lane & 15);
  const int ci0 = ks * 32 + (lane >> 4) * 8;
  ushort v[8];
  #pragma unroll
  for (int e = 0; e < 8; ++e)
    v[e] = f2bf(wg[((size_t)co * 256 + ci0 + e) * 9 + kk]);
  uint4 u;
  u.x = (uint)v[0] | ((uint)v[1] << 16);
  u.y = (uint)v[2] | ((uint)v[3] << 16);
  u.z = (uint)v[4] | ((uint)v[5] << 16);
  u.w = (uint)v[6] | ((uint)v[7] << 16);
  ((uint4*)cwswz)[t] = u;
}

// ---------------- kernel 2: 3x3 conv via bf16 MFMA -> x2p packed bf16 [BT][128][HW] ----------------
// Half-split staging (66 KB LDS, launch_bounds(512,4), r11-verified config);
// wave-local pack epilogue with packed bf16 residual from xp.

__global__ __launch_bounds__(512, 4) void k_conv_mfma(
    const ushort* __restrict__ xri, const ushort* __restrict__ cwswz,
    const float* __restrict__ bias,
    const uint* __restrict__ xp,
    uint* __restrict__ x2p) {
  __shared__ ushort xb[33792];   // 4 rows * 16 units * 66 w * 8 ci = 66 KB
  const int tid = threadIdx.x;
  const int wave = tid >> 6, lane = tid & 63;
  const int lrow = lane & 15, lgrp = lane >> 4;
  const int blk = blockIdx.x;         // 1024 = bt*32 + hp
  const int bt = blk >> 5;
  const int h0 = (blk & 31) * 2;
  const int cw = wave & 3;
  const int sg = wave >> 2;

  f32x4 acc[4][4];
  #pragma unroll
  for (int j = 0; j < 4; ++j)
    #pragma unroll
    for (int i = 0; i < 4; ++i) acc[j][i] = (f32x4)0.f;

  for (int half = 0; half < 2; ++half) {
    __syncthreads();   // protect previous half's reads
    // zero halo (w slots 0 and 65)
    if (tid < 128) {
      const int j = tid >> 5;
      const int u = (tid >> 1) & 15;
      const int wz = (tid & 1) * 65;
      uint4 z = {0u, 0u, 0u, 0u};
      *(uint4*)&xb[((j * 16 + u) * 66 + wz) * 8] = z;
    }
    // coalesced staging: 8 iters x uint4
    #pragma unroll
    for (int i = 0; i < 8; ++i) {
      const int idx = i * 512 + tid;    // 0..4095
      const int w = idx & 63;
      const int u = (idx >> 6) & 15;
      const int j = idx >> 10;          // row 0..3
      const int hh = h0 + j - 1;
      uint4 v = {0u, 0u, 0u, 0u};
      if (hh >= 0 && hh < 64)
        v = *(const uint4*)&xri[(((size_t)bt * 64 + hh) * 32 + half * 16 + u) * 512
                                + w * 8];
      *(uint4*)&xb[((j * 16 + u) * 66 + 1 + w) * 8] = v;
    }
    __syncthreads();

    for (int kh = 0; kh < 3; ++kh) {
      for (int kw = 0; kw < 3; ++kw) {
        const int kk = kh * 3 + kw;
        #pragma unroll
        for (int ks = 0; ks < 4; ++ks) {
          bf16x8 bfr[4];
          #pragma unroll
          for (int i = 0; i < 4; ++i)
            bfr[i] = *(const bf16x8*)&xb[(((sg + kh) * 16 + ks * 4 + lgrp) * 66
                                          + i * 16 + lrow + kw) * 8];
          const int fbase = ((kk * 8 + half * 4 + ks) * 16 + cw * 4) * 64 + lane;
          #pragma unroll
          for (int j = 0; j < 4; ++j) {
            const bf16x8 afr = ((const bf16x8*)cwswz)[fbase + j * 64];
            #pragma unroll
            for (int i = 0; i < 4; ++i)
              acc[j][i] = __builtin_amdgcn_mfma_f32_16x16x32_bf16(
                  afr, bfr[i], acc[j][i], 0, 0, 0);
          }
        }
      }
    }
  }

  // ---- epilogue: wave-local pack (re = acc[j], im = acc[j+2], same d), bf16 residual
  #pragma unroll
  for (int j = 0; j < 2; ++j) {
    #pragma unroll
    for (int jj = 0; jj < 4; ++jj) {
      const int d = (2 * cw + j) * 16 + lgrp * 4 + jj;   // 0..127
      const float bvr = bias[d];
      const float bvi = bias[d + 128];
      const size_t rowoff = ((size_t)bt * D_ + d) * HW_ + (h0 + sg) * W_;
      #pragma unroll
      for (int i = 0; i < 4; ++i) {
        const int w = i * 16 + lrow;
        const uint xv = xp[rowoff + w];
        const float re = acc[j][i][jj] + bvr + __uint_as_float(xv << 16);
        const float im = acc[j + 2][i][jj] + bvi + __uint_as_float(xv & 0xffff0000u);
        x2p[rowoff + w] = cvt_pk(re, im);
      }
    }
  }
}

// ---------------- decay/forcing table ----------------

__global__ __launch_bounds__(256) void k_prep_decay(
    const float* __restrict__ dt, const float* __restrict__ nu,
    const float* __restrict__ theta, float4* __restrict__ decay) {
  const int idx = blockIdx.x * 256 + threadIdx.x;  // 0..4095
  const int d = idx & 127;
  const int bt = idx >> 7;
  const float dtv = dt[bt];
  const float lr = -softplus_f(nu[d]);
  const float li = theta[d];
  float s, c;
  sincosf(li * dtv, &s, &c);
  const float er = expf(lr * dtv);
  const float ar = er * c, ai = er * s;
  const float den = lr * lr + li * li;
  const float nr = ar - 1.f, ni = ai;
  float4 v;
  v.x = ar; v.y = ai;
  v.z = (nr * lr + ni * li) / den;
  v.w = (ni * lr - nr * li) / den;
  decay[idx] = v;
}

// ---------------- temporal-encode weight prep ----------------

__global__ __launch_bounds__(256) void k_prep_enc(
    const float* __restrict__ enc_re, const float* __restrict__ enc_im,
    const float* __restrict__ g, ushort* __restrict__ encswz) {
  const int t = blockIdx.x * 256 + threadIdx.x;   // 0..8191
  const int lane = t & 63;
  const int ks = (t >> 6) & 7;
  const int ntile = t >> 9;
  const int n = ntile * 16 + (lane & 15);
  const int k0 = ks * 32 + (lane >> 4) * 8;
  ushort v[8];
  #pragma unroll
  for (int e = 0; e < 8; ++e) {
    const int kp = k0 + e;
    const int k = (kp >> 1) | ((kp & 1) << 7);   // physical -> logical
    float val;
    if (k < 128) {
      val = (n < 128) ? enc_re[k * 128 + n] : enc_im[k * 128 + (n - 128)];
    } else {
      const int kk = k - 128;
      val = (n < 128) ? -enc_im[kk * 128 + n] : enc_re[kk * 128 + (n - 128)];
    }
    v[e] = f2bf(val * g[k]);
  }
  uint4 u;
  u.x = (uint)v[0] | ((uint)v[1] << 16);
  u.y = (uint)v[2] | ((uint)v[3] << 16);
  u.z = (uint)v[4] | ((uint)v[5] << 16);
  u.w = (uint)v[6] | ((uint)v[7] << 16);
  ((uint4*)encswz)[t] = u;
}

__global__ __launch_bounds__(256) void k_prep_encvec(
    const float* __restrict__ enc_re, const float* __restrict__ enc_im,
    const float* __restrict__ g, const float* __restrict__ bb,
    float* __restrict__ evec, float* __restrict__ cvec) {
  const int n = threadIdx.x;   // one block of 256
  float se = 0.f, sc = 0.f;
  for (int k = 0; k < 256; ++k) {
    float ep;
    if (k < 128) {
      ep = (n < 128) ? enc_re[k * 128 + n] : enc_im[k * 128 + (n - 128)];
    } else {
      const int kk = k - 128;
      ep = (n < 128) ? -enc_im[kk * 128 + n] : enc_re[kk * 128 + (n - 128)];
    }
    se = fmaf(g[k], ep, se);
    sc = fmaf(bb[k], ep, sc);
  }
  evec[n] = se;
  cvec[n] = sc;
}

__global__ __launch_bounds__(256) void k_prep_dec(
    const float* __restrict__ dec_re, const float* __restrict__ dec_im,
    ushort* __restrict__ decswz) {
  const int t = blockIdx.x * 256 + threadIdx.x;   // 0..4095
  const int lane = t & 63;
  const int ks = (t >> 6) & 7;
  const int ntile = t >> 9;
  const int n = ntile * 16 + (lane & 15);
  const int k0 = ks * 32 + (lane >> 4) * 8;
  ushort v[8];
  #pragma unroll
  for (int e = 0; e < 8; ++e) {
    const int kp = k0 + e;
    const int k = (kp >> 1) | ((kp & 1) << 7);
    float val = (k < 128) ? dec_re[k * 128 + n] : -dec_im[(k - 128) * 128 + n];
    v[e] = f2bf(val);
  }
  uint4 u;
  u.x = (uint)v[0] | ((uint)v[1] << 16);
  u.y = (uint)v[2] | ((uint)v[3] << 16);
  u.z = (uint)v[4] | ((uint)v[5] << 16);
  u.w = (uint)v[6] | ((uint)v[7] << 16);
  ((uint4*)decswz)[t] = u;
}

// ---------------- kernel 3: temporal LN (folded) + encode MFMA + src + ZOH -> u32 [T][D][N] ----------------
// VGPR 112 <= 128 -> 4 blocks/CU at 35 KB LDS (launch_bounds(256,4), grid 2048 = 8/CU)

__global__ __launch_bounds__(256, 4) void k_temporal_mfma(
    const uint* __restrict__ x2p,
    const ushort* __restrict__ encswz,
    const float* __restrict__ evec, const float* __restrict__ cvec,
    const float4* __restrict__ decay,
    const float* __restrict__ src_gain,
    uint* __restrict__ u32) {
  __shared__ ushort xlds[64][256];
  __shared__ float red1[4][64], red2[4][64];
  __shared__ float mean_s[64], rstd_s[64];
  __shared__ float fre_s[128], fim_s[128], gain_s[128];
  const int tid = threadIdx.x;
  const int wave = tid >> 6, lane = tid & 63;
  const int lrow = lane & 15, lgrp = lane >> 4;
  const int blk = blockIdx.x;          // ((b*16)+t)*64 + h
  const int h = blk & 63;
  const int t = (blk >> 6) & 15;
  const int b = blk >> 10;
  const int bt = b * T_ + t;

  // stage packed x2 -> LDS (pass-through) + LN sums
  float s1 = 0.f, s2 = 0.f;
  #pragma unroll
  for (int i = 0; i < 8; ++i) {
    const int q = i * 4 + wave;        // d-quad 0..31
    const uint* src = &x2p[((size_t)bt * D_ + q * 4) * HW_ + h * W_ + lane];
    uint4 u;
    u.x = src[0];
    u.y = src[HW_];
    u.z = src[2 * HW_];
    u.w = src[3 * HW_];
    *(uint4*)&xlds[lane][(q ^ (lane & 7)) << 3] = u;
    #pragma unroll
    for (int e = 0; e < 4; ++e) {
      const uint v = ((const uint*)&u)[e];
      const float re = __uint_as_float(v << 16);
      const float im = __uint_as_float(v & 0xffff0000u);
      s1 += re + im;
      s2 += re * re + im * im;
    }
  }
  red1[wave][lane] = s1;
  red2[wave][lane] = s2;
  __syncthreads();
  if (tid < 64) {
    float m = red1[0][tid] + red1[1][tid] + red1[2][tid] + red1[3][tid];
    float ss = red2[0][tid] + red2[1][tid] + red2[2][tid] + red2[3][tid];
    m *= (1.f / 256.f);
    float var = ss * (1.f / 256.f) - m * m;
    mean_s[tid] = m;
    rstd_s[tid] = rsqrtf(var + 1e-5f);
  }
  if (tid < 128) {
    const float4 dc = decay[bt * 128 + tid];
    fre_s[tid] = dc.z;
    fim_s[tid] = dc.w;
    gain_s[tid] = src_gain[tid];
  }
  __syncthreads();

  f32x4 acc[4][4];
  #pragma unroll
  for (int ntl = 0; ntl < 4; ++ntl)
    #pragma unroll
    for (int st = 0; st < 4; ++st) acc[ntl][st] = (f32x4)0.f;

  const int swz = lrow & 7;
  const int ntb[4] = {wave * 2, wave * 2 + 1, wave * 2 + 8, wave * 2 + 9};
  #pragma unroll
  for (int ks = 0; ks < 8; ++ks) {
    bf16x8 bfr[4];
    #pragma unroll
    for (int st = 0; st < 4; ++st)
      bfr[st] = *(const bf16x8*)&xlds[st * 16 + lrow][(((ks * 4 + lgrp) ^ swz)) << 3];
    #pragma unroll
    for (int ntl = 0; ntl < 4; ++ntl) {
      const bf16x8 afr = ((const bf16x8*)encswz)[(ntb[ntl] * 8 + ks) * 64 + lane];
      #pragma unroll
      for (int st = 0; st < 4; ++st)
        acc[ntl][st] = __builtin_amdgcn_mfma_f32_16x16x32_bf16(
            afr, bfr[st], acc[ntl][st], 0, 0, 0);
    }
  }

  const int nbase = (b * 64 + h) * 64;
  #pragma unroll
  for (int ntl = 0; ntl < 2; ++ntl) {
    const int d0 = ntb[ntl] * 16 + lgrp * 4;    // <128
    #pragma unroll
    for (int st = 0; st < 4; ++st) {
      const int site = st * 16 + lrow;
      const float m = mean_s[site], rs = rstd_s[site];
      #pragma unroll
      for (int j = 0; j < 4; ++j) {
        const int d = d0 + j;
        const float xer = rs * acc[ntl][st][j] - rs * m * evec[d] + cvec[d];
        const float xei = rs * acc[ntl + 2][st][j] - rs * m * evec[d + 128] + cvec[d + 128];
        const float sr = tanh_fast(xer) * gain_s[d];
        const float si = tanh_fast(xei) * gain_s[d];
        const float vr = xer + sr, vi = xei + si;
        const float ur = vr * fre_s[d] - vi * fim_s[d];
        const float ui = vr * fim_s[d] + vi * fre_s[d];
        u32[(size_t)t * ND_ + (size_t)d * N_ + nbase + site] = cvt_pk(ur, ui);
      }
    }
  }
}

// ---------------- kernel 4: sequential scan over T (in place, packed bf16 u32 [T][D][N]) ----------------

__global__ __launch_bounds__(256) void k_scan(
    uint* __restrict__ u32, const float4* __restrict__ decay) {
  const int idx = blockIdx.x * 256 + threadIdx.x;   // d*N + n
  const int n = idx & 8191;
  const int d = idx >> 13;
  const int b = n >> 12;
  float hr = 0.f, hi = 0.f;
  #pragma unroll
  for (int t = 0; t < 16; ++t) {
    const float4 dc = decay[(b * 16 + t) * 128 + d];   // wave-uniform
    const size_t off = (size_t)t * ND_ + idx;
    const uint v = u32[off];
    const float ur = __uint_as_float(v << 16);
    const float ui = __uint_as_float(v & 0xffff0000u);
    const float nr = fmaf(dc.x, hr, fmaf(-dc.y, hi, ur));
    const float ni = fmaf(dc.x, hi, fmaf(dc.y, hr, ui));
    hr = nr; hi = ni;
    u32[off] = cvt_pk(hr, hi);
  }
}

// ---------------- FFN weight prep ----------------

__global__ __launch_bounds__(256) void k_prep_b1(
    const float* __restrict__ w1_re, const float* __restrict__ w1_im,
    ushort* __restrict__ b1swz) {
  const int t = blockIdx.x * 256 + threadIdx.x;   // 0..32767
  const int lane = t & 63;
  const int ks = (t >> 6) & 7;
  const int ntile = t >> 9;
  const int n = ntile * 16 + (lane & 15);
  const int k0 = ks * 32 + (lane >> 4) * 8;
  ushort v[8];
  #pragma unroll
  for (int e = 0; e < 8; ++e) {
    const int kp = k0 + e;
    const int k = (kp >> 1) | ((kp & 1) << 7);   // physical -> logical
    float val;
    if (k < 128) {
      val = (n < 512) ? w1_re[k * 512 + n] : w1_im[k * 512 + (n - 512)];
    } else {
      const int kk = k - 128;
      val = (n < 512) ? -w1_im[kk * 512 + n] : w1_re[kk * 512 + (n - 512)];
    }
    v[e] = f2bf(val);
  }
  uint4 u;
  u.x = (uint)v[0] | ((uint)v[1] << 16);
  u.y = (uint)v[2] | ((uint)v[3] << 16);
  u.z = (uint)v[4] | ((uint)v[5] << 16);
  u.w = (uint)v[6] | ((uint)v[7] << 16);
  ((uint4*)b1swz)[t] = u;
}

__global__ __launch_bounds__(256) void k_prep_b2(
    const float* __restrict__ w2_re, const float* __restrict__ w2_im,
    ushort* __restrict__ b2swz) {
  const int t = blockIdx.x * 256 + threadIdx.x;   // 0..32767
  const int lane = t & 63;
  const int kc = (t >> 6) & 31;
  const int rowtile = t >> 11;
  const int n2 = rowtile * 16 + (lane & 15);
  const int k0 = kc * 32 + (lane >> 4) * 8;
  ushort v[8];
  #pragma unroll
  for (int e = 0; e < 8; ++e) {
    const int k = k0 + e;                       // act layout: no permute
    float val;
    if (k < 512) {
      val = (n2 < 128) ? w2_re[k * 128 + n2] : w2_im[k * 128 + (n2 - 128)];
    } else {
      const int kk = k - 512;
      val = (n2 < 128) ? -w2_im[kk * 128 + n2] : w2_re[kk * 128 + (n2 - 128)];
    }
    v[e] = f2bf(val);
  }
  uint4 u;
  u.x = (uint)v[0] | ((uint)v[1] << 16);
  u.y = (uint)v[2] | ((uint)v[3] << 16);
  u.z = (uint)v[4] | ((uint)v[5] << 16);
  u.w = (uint)v[6] | ((uint)v[7] << 16);
  ((uint4*)b2swz)[t] = u;
}

// ---------------- kernel 6: drift-decode (fused) + complex FFN via bf16 MFMA ----------------

__global__ __launch_bounds__(256, 2) void k_ffn_mfma(
    const uint* __restrict__ x2p, const uint* __restrict__ h32,
    const ushort* __restrict__ decswz,
    const ushort* __restrict__ b1swz, const ushort* __restrict__ b2swz,
    const float* __restrict__ b1_re, const float* __restrict__ b1_im,
    const float* __restrict__ b2_re, const float* __restrict__ b2_im,
    float* __restrict__ out) {
  __shared__ ushort xlds[64][256];
  __shared__ ushort actlds[2][64][136];
  const int tid = threadIdx.x;
  const int wave = tid >> 6, lane = tid & 63;
  const int lrow = lane & 15, lgrp = lane >> 4;
  const int blk = blockIdx.x;        // 2048 = bt*64 + h
  const int bt = blk >> 6;
  const int hrow = blk & 63;
  const int hw0 = hrow * 64;
  const int b = bt >> 4, t = bt & 15;
  const int nbase = (b * 64 + hrow) * 64;
  const bf16x8* b1f = (const bf16x8*)b1swz;
  const bf16x8* b2f = (const bf16x8*)b2swz;
  const bf16x8* dcf = (const bf16x8*)decswz;
  ushort* hbuf = &actlds[0][0][0];   // [64 site][264 pad] view, dead before chunk 0

  // stage x2 (packed, pass-through) and h (packed)
  #pragma unroll
  for (int i = 0; i < 8; ++i) {
    const int q = i * 4 + wave;        // d-quad 0..31
    const uint* src = &x2p[((size_t)bt * D_ + q * 4) * HW_ + hw0 + lane];
    uint4 u;
    u.x = src[0]; u.y = src[HW_]; u.z = src[2 * HW_]; u.w = src[3 * HW_];
    *(uint4*)&xlds[lane][(q ^ (lane & 7)) << 3] = u;
  }
  #pragma unroll
  for (int i = 0; i < 8; ++i) {
    const int q = i * 4 + wave;
    const size_t o = (size_t)t * ND_ + (size_t)(q * 4) * N_ + nbase + lane;
    uint4 u;
    u.x = h32[o]; u.y = h32[o + N_]; u.z = h32[o + 2 * N_]; u.w = h32[o + 3 * N_];
    *(uint4*)&hbuf[lane * 264 + ((q ^ (lane & 7)) << 3)] = u;
  }

  // prefetch chunk-0 A-fragments
  bf16x8 a1[2][8];
  #pragma unroll
  for (int ntl = 0; ntl < 2; ++ntl)
    #pragma unroll
    for (int ks = 0; ks < 8; ++ks)
      a1[ntl][ks] = b1f[((wave * 2 + ntl) * 8 + ks) * 64 + lane];
  bf16x8 a2[4][2];
  #pragma unroll
  for (int rt = 0; rt < 4; ++rt)
    #pragma unroll
    for (int k2 = 0; k2 < 2; ++k2)
      a2[rt][k2] = b2f[((wave * 4 + rt) * 32 + k2) * 64 + lane];

  __syncthreads();
  const int swz = lrow & 7;

  // ---- fused decode: drift = h @ decP (real), RMW into xlds re-halves
  {
    f32x4 dr[2][4];
    #pragma unroll
    for (int ntl = 0; ntl < 2; ++ntl)
      #pragma unroll
      for (int st = 0; st < 4; ++st) dr[ntl][st] = (f32x4)0.f;
    #pragma unroll
    for (int ks = 0; ks < 8; ++ks) {
      bf16x8 bfr[4];
      #pragma unroll
      for (int st = 0; st < 4; ++st)
        bfr[st] = *(const bf16x8*)&hbuf[(st * 16 + lrow) * 264
                                        + (((ks * 4 + lgrp) ^ swz) << 3)];
      #pragma unroll
      for (int ntl = 0; ntl < 2; ++ntl) {
        const bf16x8 afr = dcf[((wave * 2 + ntl) * 8 + ks) * 64 + lane];
        #pragma unroll
        for (int st = 0; st < 4; ++st)
          dr[ntl][st] = __builtin_amdgcn_mfma_f32_16x16x32_bf16(
              afr, bfr[st], dr[ntl][st], 0, 0, 0);
      }
    }
    #pragma unroll
    for (int ntl = 0; ntl < 2; ++ntl) {
      #pragma unroll
      for (int st = 0; st < 4; ++st) {
        const int site = st * 16 + lrow;
        #pragma unroll
        for (int j = 0; j < 4; ++j) {
          const int d = (wave * 2 + ntl) * 16 + lgrp * 4 + j;
          ushort* p = &xlds[site][(((d >> 2) ^ (site & 7)) << 3) + (d & 3) * 2];
          const uint v = *(uint*)p;
          const float re = __uint_as_float(v << 16) + dr[ntl][st][j];
          *(uint*)p = (v & 0xffff0000u) | (uint)f2bf(re);
        }
      }
    }
  }
  __syncthreads();   // xlds now holds x3; hbuf (actlds) free

  f32x4 dacc[4][4];
  #pragma unroll
  for (int rt = 0; rt < 4; ++rt)
    #pragma unroll
    for (int st = 0; st < 4; ++st) dacc[rt][st] = (f32x4)0.f;

  for (int chunk = 0; chunk < 8; ++chunk) {
    const int nc = (chunk + 1) & 7;

    // ---- GEMM1(chunk)
    f32x4 hacc[2][4];
    #pragma unroll
    for (int ntl = 0; ntl < 2; ++ntl)
      #pragma unroll
      for (int st = 0; st < 4; ++st) hacc[ntl][st] = (f32x4)0.f;

    #pragma unroll
    for (int ks = 0; ks < 8; ++ks) {
      bf16x8 bfr[4];
      #pragma unroll
      for (int st = 0; st < 4; ++st)
        bfr[st] = *(const bf16x8*)&xlds[st * 16 + lrow][(((ks * 4 + lgrp) ^ swz)) << 3];
      #pragma unroll
      for (int ntl = 0; ntl < 2; ++ntl)
        #pragma unroll
        for (int st = 0; st < 4; ++st)
          hacc[ntl][st] = __builtin_amdgcn_mfma_f32_16x16x32_bf16(
              a1[ntl][ks], bfr[st], hacc[ntl][st], 0, 0, 0);
    }

    // ---- prefetch a1 for next chunk
    #pragma unroll
    for (int ntl = 0; ntl < 2; ++ntl)
      #pragma unroll
      for (int ks = 0; ks < 8; ++ks)
        a1[ntl][ks] = b1f[((nc * 8 + wave * 2 + ntl) * 8 + ks) * 64 + lane];

    // ---- bias + gelu -> act[chunk&1]
    uint* act32 = (uint*)&actlds[chunk & 1][0][0];
    #pragma unroll
    for (int ntl = 0; ntl < 2; ++ntl) {
      const int nlocal0 = (wave * 2 + ntl) * 16 + lgrp * 4;
      const int ng0 = chunk * 128 + nlocal0;
      #pragma unroll
      for (int st = 0; st < 4; ++st) {
        float gv[4];
        #pragma unroll
        for (int j = 0; j < 4; ++j) {
          const int ng = ng0 + j;
          const float bias = (ng < 512) ? b1_re[ng] : b1_im[ng - 512];
          gv[j] = gelu_fast(hacc[ntl][st][j] + bias);
        }
        const int site = st * 16 + lrow;
        act32[site * 68 + (nlocal0 >> 1)] = cvt_pk(gv[0], gv[1]);
        act32[site * 68 + (nlocal0 >> 1) + 1] = cvt_pk(gv[2], gv[3]);
      }
    }

    // ---- load this chunk's GEMM2 ks2 2-3 frags
    bf16x8 a2b[4][2];
    #pragma unroll
    for (int rt = 0; rt < 4; ++rt)
      #pragma unroll
      for (int k2 = 0; k2 < 2; ++k2)
        a2b[rt][k2] = b2f[((wave * 4 + rt) * 32 + chunk * 4 + 2 + k2) * 64 + lane];

    __syncthreads();   // act[chunk&1] ready (one barrier/chunk)

    // ---- GEMM2(chunk)
    const ushort* actb = &actlds[chunk & 1][0][0];
    #pragma unroll
    for (int ks2 = 0; ks2 < 2; ++ks2) {
      bf16x8 bfr[4];
      #pragma unroll
      for (int st = 0; st < 4; ++st)
        bfr[st] = *(const bf16x8*)&actb[(st * 16 + lrow) * 136 + ks2 * 32 + lgrp * 8];
      #pragma unroll
      for (int rt = 0; rt < 4; ++rt)
        #pragma unroll
        for (int st = 0; st < 4; ++st)
          dacc[rt][st] = __builtin_amdgcn_mfma_f32_16x16x32_bf16(
              a2[rt][ks2], bfr[st], dacc[rt][st], 0, 0, 0);
    }
    #pragma unroll
    for (int ks2 = 0; ks2 < 2; ++ks2) {
      bf16x8 bfr[4];
      #pragma unroll
      for (int st = 0; st < 4; ++st)
        bfr[st] = *(const bf16x8*)&actb[(st * 16 + lrow) * 136 + (ks2 + 2) * 32 + lgrp * 8];
      #pragma unroll
      for (int rt = 0; rt < 4; ++rt)
        #pragma unroll
        for (int st = 0; st < 4; ++st)
          dacc[rt][st] = __builtin_amdgcn_mfma_f32_16x16x32_bf16(
              a2b[rt][ks2], bfr[st], dacc[rt][st], 0, 0, 0);
    }

    // ---- prefetch next chunk's GEMM2 ks2 0-1 frags
    #pragma unroll
    for (int rt = 0; rt < 4; ++rt)
      #pragma unroll
      for (int k2 = 0; k2 < 2; ++k2)
        a2[rt][k2] = b2f[((wave * 4 + rt) * 32 + nc * 4 + k2) * 64 + lane];
  }

  // epilogue: residual x3 from xlds, bias2, interleaved [.,2] output
  #pragma unroll
  for (int rt = 0; rt < 4; ++rt) {
    #pragma unroll
    for (int j = 0; j < 4; ++j) {
      const int n2 = (wave * 4 + rt) * 16 + lgrp * 4 + j;
      const int d = n2 & 127;
      const int c = n2 >> 7;
      const float bias2 = c ? b2_im[d] : b2_re[d];
      #pragma unroll
      for (int st = 0; st < 4; ++st) {
        const int site = st * 16 + lrow;
        const uint pr = *(const uint*)&xlds[site][(((d >> 2) ^ (site & 7)) << 3)
                                                  + (d & 3) * 2];
        const float rv = c ? __uint_as_float(pr & 0xffff0000u)
                           : __uint_as_float(pr << 16);
        const size_t idx = (size_t)(bt * D_ + d) * HW_ + hw0 + site;
        out[idx * 2 + c] = rv + dacc[rt][st][j] + bias2;
      }
    }
  }
}

// ---------------- host launcher ----------------

extern "C" void kernel_launch(void* const* d_in, const int* in_sizes, int n_in,
                              void* d_out, int out_size, void* d_ws, size_t ws_size,
                              hipStream_t stream) {
  const float* x_re   = (const float*)d_in[0];
  const float* x_im   = (const float*)d_in[1];
  const float* dt     = (const float*)d_in[2];
  const float* ln_s_g = (const float*)d_in[3];
  const float* ln_s_b = (const float*)d_in[4];
  const float* ln_t_g = (const float*)d_in[5];
  const float* ln_t_b = (const float*)d_in[6];
  const float* metric = (const float*)d_in[7];
  const float* conv_w = (const float*)d_in[8];
  const float* conv_b = (const float*)d_in[9];
  const float* nu     = (const float*)d_in[10];
  const float* theta  = (const float*)d_in[11];
  const float* enc_re = (const float*)d_in[12];
  const float* enc_im = (const float*)d_in[13];
  const float* dec_re = (const float*)d_in[14];
  const float* dec_im = (const float*)d_in[15];
  const float* src_g  = (const float*)d_in[16];
  const float* w1_re  = (const float*)d_in[17];
  const float* w1_im  = (const float*)d_in[18];
  const float* b1_re  = (const float*)d_in[19];
  const float* b1_im  = (const float*)d_in[20];
  const float* w2_re  = (const float*)d_in[21];
  const float* w2_im  = (const float*)d_in[22];
  const float* b2_re  = (const float*)d_in[23];
  const float* b2_im  = (const float*)d_in[24];
  float* out = (float*)d_out;
  float* ws = (float*)d_ws;

  // workspace layout
  float* wt   = ws;                          // weight-prep region (~2.5 MB)
  float* bufA = ws + WT_FLOATS;
  ushort* wt16  = (ushort*)wt;
  ushort* cwswz = wt16;                      // conv frags (dead after conv)
  ushort* b1swz = wt16;                      // FFN frags (overwrite after conv)
  ushort* b2swz = wt16 + 262144;
  ushort* encswz = wt16 + 524288;
  ushort* decswz = wt16 + 589824;
  float*  evec   = (float*)(wt16 + 622592);
  float*  cvec   = evec + 256;
  float4* decay  = (float4*)(cvec + 256);    // 64 KB
  ushort* xri_bf = (ushort*)bufA;            // 67 MB (dead after conv)

  // planA: xri | u32(+128KB skew over xri) | x2p(+256KB skew) | xp(+512KB skew)
  const size_t needA = ((size_t)WT_FLOATS + 3 * (size_t)PLANE_) * 4 + (2u << 20);
  const bool planA = ws_size >= needA;
  uint *u32p, *x2p, *xp;
  float* ffn_out;
  if (planA) {
    u32p = (uint*)bufA + 32768;                      // overwrites dead xri (skewed)
    x2p  = (uint*)bufA + PLANE_ + 65536;
    xp   = (uint*)bufA + 2 * (size_t)PLANE_ + 131072;
    ffn_out = out;
  } else {
    // route u32/x2p through d_out; xp in ws after xri; final d2d copy
    u32p = (uint*)out;
    x2p  = (uint*)out + PLANE_;
    xp   = (uint*)bufA + PLANE_;
    ffn_out = bufA;
  }

  k_prep_conv<<<288, 256, 0, stream>>>(conv_w, cwswz);
  k_prep_decay<<<16, 256, 0, stream>>>(dt, nu, theta, decay);
  k_spatial_ln<<<BT_ * H_, 256, 0, stream>>>(x_re, x_im, ln_s_g, ln_s_b, metric,
                                             xri_bf, xp);
  k_conv_mfma<<<BT_ * 32, 512, 0, stream>>>(xri_bf, cwswz, conv_b, xp, x2p);
  // cwswz dead after conv; overwrite region with GEMM weights
  k_prep_b1<<<128, 256, 0, stream>>>(w1_re, w1_im, b1swz);
  k_prep_b2<<<128, 256, 0, stream>>>(w2_re, w2_im, b2swz);
  k_prep_enc<<<32, 256, 0, stream>>>(enc_re, enc_im, ln_t_g, encswz);
  k_prep_encvec<<<1, 256, 0, stream>>>(enc_re, enc_im, ln_t_g, ln_t_b, evec, cvec);
  k_prep_dec<<<16, 256, 0, stream>>>(dec_re, dec_im, decswz);
  k_temporal_mfma<<<B_ * T_ * H_, 256, 0, stream>>>(x2p, encswz, evec, cvec,
                                                    decay, src_g, u32p);
  k_scan<<<ND_ / 256, 256, 0, stream>>>(u32p, decay);
  k_ffn_mfma<<<BT_ * H_, 256, 0, stream>>>(x2p, u32p, decswz, b1swz, b2swz,
                                           b1_re, b1_im, b2_re, b2_im, ffn_out);
  if (!planA) {
    hipMemcpyAsync(d_out, ffn_out, (size_t)2 * PLANE_ * sizeof(float),
                   hipMemcpyDeviceToDevice, stream);
  }
}

// Round 14
// 657.760 us; speedup vs baseline: 1.0275x; 1.0117x over previous
//
#include <hip/hip_runtime.h>
#include <hip/hip_bf16.h>
#include <stdint.h>

#define B_   2
#define T_   16
#define D_   128
#define D2_  256
#define H_   64
#define W_   64
#define HW_  4096
#define BT_  32
#define N_   8192
#define ND_  1048576           // N_*D_
#define PLANE_ 16777216        // B*T*D*H*W  (one of re/im)
#define PREP_FLOATS 655360     // prep region: 2.5 MB

typedef short bf16x8 __attribute__((ext_vector_type(8)));
typedef float f32x4 __attribute__((ext_vector_type(4)));
typedef unsigned int uint;
typedef unsigned short ushort;

// ---------------- device helpers ----------------

__device__ __forceinline__ float softplus_f(float x) {
  return fmaxf(x, 0.0f) + log1pf(expf(-fabsf(x)));
}

__device__ __forceinline__ float gelu_fast(float x) {
  const float Ac = 2.3022082963f;   // 2*sqrt(2/pi)*log2(e)
  const float Bc = 0.1029437f;      // Ac*0.044715
  float t = x * x;
  float z = x * fmaf(Bc, t, Ac);
  float e = __builtin_amdgcn_exp2f(z);
  float r = __builtin_amdgcn_rcpf(e + 1.0f);
  return fmaf(-x, r, x);
}

__device__ __forceinline__ float tanh_fast(float x) {
  float e = __builtin_amdgcn_exp2f(x * 2.8853900818f);  // 2*log2(e)
  float r = __builtin_amdgcn_rcpf(e + 1.0f);
  return fmaf(-2.0f, r, 1.0f);
}

__device__ __forceinline__ ushort f2bf(float f) {
  uint u = __float_as_uint(f);
  uint r = (u + 0x7fffu + ((u >> 16) & 1u)) >> 16;   // RNE
  return (ushort)r;
}

__device__ __forceinline__ uint cvt_pk(float a, float b) {
  __hip_bfloat162 h = __float22bfloat162_rn(make_float2(a, b));
  return *reinterpret_cast<uint*>(&h);
}

__device__ __forceinline__ uint4 pack8(const ushort v[8]) {
  uint4 u;
  u.x = (uint)v[0] | ((uint)v[1] << 16);
  u.y = (uint)v[2] | ((uint)v[3] << 16);
  u.z = (uint)v[4] | ((uint)v[5] << 16);
  u.w = (uint)v[6] | ((uint)v[7] << 16);
  return u;
}

// ---------------- kernel 0: ALL weight prep in one launch ----------------
// blocks [0,288): conv frags | [288,304): decay | [304,432): b1 | [432,560): b2
// [560,592): enc | [592,593): encvec | [593,609): dec

__global__ __launch_bounds__(256) void k_prep_all(
    const float* __restrict__ wg,
    const float* __restrict__ dt, const float* __restrict__ nu,
    const float* __restrict__ theta,
    const float* __restrict__ w1_re, const float* __restrict__ w1_im,
    const float* __restrict__ w2_re, const float* __restrict__ w2_im,
    const float* __restrict__ enc_re, const float* __restrict__ enc_im,
    const float* __restrict__ dec_re, const float* __restrict__ dec_im,
    const float* __restrict__ g, const float* __restrict__ bb,
    ushort* __restrict__ cwswz, float4* __restrict__ decay,
    ushort* __restrict__ b1swz, ushort* __restrict__ b2swz,
    ushort* __restrict__ encswz, ushort* __restrict__ decswz,
    float* __restrict__ evec, float* __restrict__ cvec) {
  const int blk = blockIdx.x;
  const int tid = threadIdx.x;

  if (blk < 288) {                       // ---- conv frags (remapped tile order)
    const int t = blk * 256 + tid;
    if (t >= 73728) return;
    const int lane = t & 63;
    const int nt = (t >> 6) & 15;
    const int ks = (t >> 10) & 7;
    const int kk = t >> 13;
    const int cwv = nt >> 2, jjv = nt & 3;
    const int co_tile = (jjv < 2) ? (2 * cwv + jjv) : (8 + 2 * cwv + (jjv - 2));
    const int co = co_tile * 16 + (lane & 15);
    const int ci0 = ks * 32 + (lane >> 4) * 8;
    ushort v[8];
    #pragma unroll
    for (int e = 0; e < 8; ++e)
      v[e] = f2bf(wg[((size_t)co * 256 + ci0 + e) * 9 + kk]);
    ((uint4*)cwswz)[t] = pack8(v);
  } else if (blk < 304) {                // ---- decay/forcing table
    const int idx = (blk - 288) * 256 + tid;
    const int d = idx & 127;
    const int bt = idx >> 7;
    const float dtv = dt[bt];
    const float lr = -softplus_f(nu[d]);
    const float li = theta[d];
    float s, c;
    sincosf(li * dtv, &s, &c);
    const float er = expf(lr * dtv);
    const float ar = er * c, ai = er * s;
    const float den = lr * lr + li * li;
    const float nr = ar - 1.f, ni = ai;
    float4 v;
    v.x = ar; v.y = ai;
    v.z = (nr * lr + ni * li) / den;
    v.w = (ni * lr - nr * li) / den;
    decay[idx] = v;
  } else if (blk < 432) {                // ---- FFN B1 frags (k-permuted)
    const int t = (blk - 304) * 256 + tid;
    const int lane = t & 63;
    const int ks = (t >> 6) & 7;
    const int ntile = t >> 9;
    const int n = ntile * 16 + (lane & 15);
    const int k0 = ks * 32 + (lane >> 4) * 8;
    ushort v[8];
    #pragma unroll
    for (int e = 0; e < 8; ++e) {
      const int kp = k0 + e;
      const int k = (kp >> 1) | ((kp & 1) << 7);
      float val;
      if (k < 128) {
        val = (n < 512) ? w1_re[k * 512 + n] : w1_im[k * 512 + (n - 512)];
      } else {
        const int kk = k - 128;
        val = (n < 512) ? -w1_im[kk * 512 + n] : w1_re[kk * 512 + (n - 512)];
      }
      v[e] = f2bf(val);
    }
    ((uint4*)b1swz)[t] = pack8(v);
  } else if (blk < 560) {                // ---- FFN B2 frags
    const int t = (blk - 432) * 256 + tid;
    const int lane = t & 63;
    const int kc = (t >> 6) & 31;
    const int rowtile = t >> 11;
    const int n2 = rowtile * 16 + (lane & 15);
    const int k0 = kc * 32 + (lane >> 4) * 8;
    ushort v[8];
    #pragma unroll
    for (int e = 0; e < 8; ++e) {
      const int k = k0 + e;
      float val;
      if (k < 512) {
        val = (n2 < 128) ? w2_re[k * 128 + n2] : w2_im[k * 128 + (n2 - 128)];
      } else {
        const int kk = k - 512;
        val = (n2 < 128) ? -w2_im[kk * 128 + n2] : w2_re[kk * 128 + (n2 - 128)];
      }
      v[e] = f2bf(val);
    }
    ((uint4*)b2swz)[t] = pack8(v);
  } else if (blk < 592) {                // ---- enc frags (g-scaled, k-permuted)
    const int t = (blk - 560) * 256 + tid;
    const int lane = t & 63;
    const int ks = (t >> 6) & 7;
    const int ntile = t >> 9;
    const int n = ntile * 16 + (lane & 15);
    const int k0 = ks * 32 + (lane >> 4) * 8;
    ushort v[8];
    #pragma unroll
    for (int e = 0; e < 8; ++e) {
      const int kp = k0 + e;
      const int k = (kp >> 1) | ((kp & 1) << 7);
      float val;
      if (k < 128) {
        val = (n < 128) ? enc_re[k * 128 + n] : enc_im[k * 128 + (n - 128)];
      } else {
        const int kk = k - 128;
        val = (n < 128) ? -enc_im[kk * 128 + n] : enc_re[kk * 128 + (n - 128)];
      }
      v[e] = f2bf(val * g[k]);
    }
    ((uint4*)encswz)[t] = pack8(v);
  } else if (blk < 593) {                // ---- evec/cvec
    const int n = tid;
    float se = 0.f, sc = 0.f;
    for (int k = 0; k < 256; ++k) {
      float ep;
      if (k < 128) {
        ep = (n < 128) ? enc_re[k * 128 + n] : enc_im[k * 128 + (n - 128)];
      } else {
        const int kk = k - 128;
        ep = (n < 128) ? -enc_im[kk * 128 + n] : enc_re[kk * 128 + (n - 128)];
      }
      se = fmaf(g[k], ep, se);
      sc = fmaf(bb[k], ep, sc);
    }
    evec[n] = se;
    cvec[n] = sc;
  } else {                               // ---- dec frags (real-part, k-permuted)
    const int t = (blk - 593) * 256 + tid;
    const int lane = t & 63;
    const int ks = (t >> 6) & 7;
    const int ntile = t >> 9;
    const int n = ntile * 16 + (lane & 15);
    const int k0 = ks * 32 + (lane >> 4) * 8;
    ushort v[8];
    #pragma unroll
    for (int e = 0; e < 8; ++e) {
      const int kp = k0 + e;
      const int k = (kp >> 1) | ((kp & 1) << 7);
      float val = (k < 128) ? dec_re[k * 128 + n] : -dec_im[(k - 128) * 128 + n];
      v[e] = f2bf(val);
    }
    ((uint4*)decswz)[t] = pack8(v);
  }
}

// ---------------- kernel 1: spatial complex LN + metric -> xri bf16 [BT][H][32u][64w][8ci]
//                  + packed raw residual xp [BT][128][HW] (re,im bf16) ----------------

__global__ __launch_bounds__(256) void k_spatial_ln(
    const float* __restrict__ x_re, const float* __restrict__ x_im,
    const float* __restrict__ g, const float* __restrict__ bb,
    const float* __restrict__ metric, ushort* __restrict__ xri,
    uint* __restrict__ xp) {
  __shared__ float vals[256][64];
  __shared__ float red1[4][64];
  __shared__ float red2[4][64];
  __shared__ float mean_s[64];
  __shared__ float rstd_s[64];
  const int blk = blockIdx.x;      // bt*64 + h
  const int bt = blk >> 6;
  const int h = blk & 63;
  const int tid = threadIdx.x;
  const int w = tid & 63, q = tid >> 6;

  const float* src = (q < 2) ? x_re : x_im;   // wave-uniform
  float s1 = 0.f, s2 = 0.f;
  #pragma unroll 4
  for (int i = 0; i < 64; ++i) {
    const int c = q * 64 + i;
    const int d = c & 127;
    float v = src[((size_t)bt * D_ + d) * HW_ + h * W_ + w];
    vals[c][w] = v;
    s1 += v; s2 += v * v;
  }
  red1[q][w] = s1; red2[q][w] = s2;
  __syncthreads();
  if (tid < 64) {
    float m = red1[0][tid] + red1[1][tid] + red1[2][tid] + red1[3][tid];
    float ss = red2[0][tid] + red2[1][tid] + red2[2][tid] + red2[3][tid];
    m *= (1.f / 256.f);
    float var = ss * (1.f / 256.f) - m * m;
    mean_s[tid] = m;
    rstd_s[tid] = rsqrtf(var + 1e-5f);
  }
  __syncthreads();
  // packed raw residual: all 256 threads, 32 d's each
  #pragma unroll
  for (int i = 0; i < 32; ++i) {
    const int d = q * 32 + i;
    xp[((size_t)bt * D_ + d) * HW_ + h * W_ + w] =
        cvt_pk(vals[d][w], vals[d + 128][w]);
  }
  const float m = mean_s[w], rs = rstd_s[w];
  const size_t ubase = (((size_t)bt * 64 + h) * 32 + q * 8) * 512 + w * 8;
  #pragma unroll
  for (int j = 0; j < 8; ++j) {
    uint4 u;
    #pragma unroll
    for (int e2 = 0; e2 < 4; ++e2) {
      const int c0 = q * 64 + j * 8 + e2 * 2;
      float v0 = (vals[c0][w] - m) * rs * g[c0] + bb[c0];
      v0 *= metric[(size_t)c0 * HW_ + h * W_ + w];
      float v1 = (vals[c0 + 1][w] - m) * rs * g[c0 + 1] + bb[c0 + 1];
      v1 *= metric[(size_t)(c0 + 1) * HW_ + h * W_ + w];
      ((uint*)&u)[e2] = cvt_pk(v0, v1);
    }
    *(uint4*)&xri[ubase + (size_t)j * 512] = u;
  }
}

// ---------------- kernel 2: 3x3 conv via bf16 MFMA -> x2p packed bf16 [BT][128][HW] ----------------
// Half-split staging (66 KB LDS, launch_bounds(512,4), r11-verified config);
// wave-local pack epilogue with packed bf16 residual from xp.

__global__ __launch_bounds__(512, 4) void k_conv_mfma(
    const ushort* __restrict__ xri, const ushort* __restrict__ cwswz,
    const float* __restrict__ bias,
    const uint* __restrict__ xp,
    uint* __restrict__ x2p) {
  __shared__ ushort xb[33792];   // 4 rows * 16 units * 66 w * 8 ci = 66 KB
  const int tid = threadIdx.x;
  const int wave = tid >> 6, lane = tid & 63;
  const int lrow = lane & 15, lgrp = lane >> 4;
  const int blk = blockIdx.x;         // 1024 = bt*32 + hp
  const int bt = blk >> 5;
  const int h0 = (blk & 31) * 2;
  const int cw = wave & 3;
  const int sg = wave >> 2;

  f32x4 acc[4][4];
  #pragma unroll
  for (int j = 0; j < 4; ++j)
    #pragma unroll
    for (int i = 0; i < 4; ++i) acc[j][i] = (f32x4)0.f;

  for (int half = 0; half < 2; ++half) {
    __syncthreads();   // protect previous half's reads
    // zero halo (w slots 0 and 65)
    if (tid < 128) {
      const int j = tid >> 5;
      const int u = (tid >> 1) & 15;
      const int wz = (tid & 1) * 65;
      uint4 z = {0u, 0u, 0u, 0u};
      *(uint4*)&xb[((j * 16 + u) * 66 + wz) * 8] = z;
    }
    // coalesced staging: 8 iters x uint4
    #pragma unroll
    for (int i = 0; i < 8; ++i) {
      const int idx = i * 512 + tid;    // 0..4095
      const int w = idx & 63;
      const int u = (idx >> 6) & 15;
      const int j = idx >> 10;          // row 0..3
      const int hh = h0 + j - 1;
      uint4 v = {0u, 0u, 0u, 0u};
      if (hh >= 0 && hh < 64)
        v = *(const uint4*)&xri[(((size_t)bt * 64 + hh) * 32 + half * 16 + u) * 512
                                + w * 8];
      *(uint4*)&xb[((j * 16 + u) * 66 + 1 + w) * 8] = v;
    }
    __syncthreads();

    for (int kh = 0; kh < 3; ++kh) {
      for (int kw = 0; kw < 3; ++kw) {
        const int kk = kh * 3 + kw;
        #pragma unroll
        for (int ks = 0; ks < 4; ++ks) {
          bf16x8 bfr[4];
          #pragma unroll
          for (int i = 0; i < 4; ++i)
            bfr[i] = *(const bf16x8*)&xb[(((sg + kh) * 16 + ks * 4 + lgrp) * 66
                                          + i * 16 + lrow + kw) * 8];
          const int fbase = ((kk * 8 + half * 4 + ks) * 16 + cw * 4) * 64 + lane;
          #pragma unroll
          for (int j = 0; j < 4; ++j) {
            const bf16x8 afr = ((const bf16x8*)cwswz)[fbase + j * 64];
            #pragma unroll
            for (int i = 0; i < 4; ++i)
              acc[j][i] = __builtin_amdgcn_mfma_f32_16x16x32_bf16(
                  afr, bfr[i], acc[j][i], 0, 0, 0);
          }
        }
      }
    }
  }

  // ---- epilogue: wave-local pack (re = acc[j], im = acc[j+2], same d), bf16 residual
  #pragma unroll
  for (int j = 0; j < 2; ++j) {
    #pragma unroll
    for (int jj = 0; jj < 4; ++jj) {
      const int d = (2 * cw + j) * 16 + lgrp * 4 + jj;   // 0..127
      const float bvr = bias[d];
      const float bvi = bias[d + 128];
      const size_t rowoff = ((size_t)bt * D_ + d) * HW_ + (h0 + sg) * W_;
      #pragma unroll
      for (int i = 0; i < 4; ++i) {
        const int w = i * 16 + lrow;
        const uint xv = xp[rowoff + w];
        const float re = acc[j][i][jj] + bvr + __uint_as_float(xv << 16);
        const float im = acc[j + 2][i][jj] + bvi + __uint_as_float(xv & 0xffff0000u);
        x2p[rowoff + w] = cvt_pk(re, im);
      }
    }
  }
}

// ---------------- kernel 3: temporal LN (folded) + encode MFMA + src + ZOH -> u32 [T][D][N] ----------------

__global__ __launch_bounds__(256, 2) void k_temporal_mfma(
    const uint* __restrict__ x2p,
    const ushort* __restrict__ encswz,
    const float* __restrict__ evec, const float* __restrict__ cvec,
    const float4* __restrict__ decay,
    const float* __restrict__ src_gain,
    uint* __restrict__ u32) {
  __shared__ ushort xlds[64][256];
  __shared__ float red1[4][64], red2[4][64];
  __shared__ float mean_s[64], rstd_s[64];
  __shared__ float fre_s[128], fim_s[128], gain_s[128];
  const int tid = threadIdx.x;
  const int wave = tid >> 6, lane = tid & 63;
  const int lrow = lane & 15, lgrp = lane >> 4;
  const int blk = blockIdx.x;          // ((b*16)+t)*64 + h
  const int h = blk & 63;
  const int t = (blk >> 6) & 15;
  const int b = blk >> 10;
  const int bt = b * T_ + t;

  // stage packed x2 -> LDS (pass-through) + LN sums
  float s1 = 0.f, s2 = 0.f;
  #pragma unroll
  for (int i = 0; i < 8; ++i) {
    const int q = i * 4 + wave;        // d-quad 0..31
    const uint* src = &x2p[((size_t)bt * D_ + q * 4) * HW_ + h * W_ + lane];
    uint4 u;
    u.x = src[0];
    u.y = src[HW_];
    u.z = src[2 * HW_];
    u.w = src[3 * HW_];
    *(uint4*)&xlds[lane][(q ^ (lane & 7)) << 3] = u;
    #pragma unroll
    for (int e = 0; e < 4; ++e) {
      const uint v = ((const uint*)&u)[e];
      const float re = __uint_as_float(v << 16);
      const float im = __uint_as_float(v & 0xffff0000u);
      s1 += re + im;
      s2 += re * re + im * im;
    }
  }
  red1[wave][lane] = s1;
  red2[wave][lane] = s2;
  __syncthreads();
  if (tid < 64) {
    float m = red1[0][tid] + red1[1][tid] + red1[2][tid] + red1[3][tid];
    float ss = red2[0][tid] + red2[1][tid] + red2[2][tid] + red2[3][tid];
    m *= (1.f / 256.f);
    float var = ss * (1.f / 256.f) - m * m;
    mean_s[tid] = m;
    rstd_s[tid] = rsqrtf(var + 1e-5f);
  }
  if (tid < 128) {
    const float4 dc = decay[bt * 128 + tid];
    fre_s[tid] = dc.z;
    fim_s[tid] = dc.w;
    gain_s[tid] = src_gain[tid];
  }
  __syncthreads();

  f32x4 acc[4][4];
  #pragma unroll
  for (int ntl = 0; ntl < 4; ++ntl)
    #pragma unroll
    for (int st = 0; st < 4; ++st) acc[ntl][st] = (f32x4)0.f;

  const int swz = lrow & 7;
  const int ntb[4] = {wave * 2, wave * 2 + 1, wave * 2 + 8, wave * 2 + 9};
  #pragma unroll
  for (int ks = 0; ks < 8; ++ks) {
    bf16x8 bfr[4];
    #pragma unroll
    for (int st = 0; st < 4; ++st)
      bfr[st] = *(const bf16x8*)&xlds[st * 16 + lrow][(((ks * 4 + lgrp) ^ swz)) << 3];
    #pragma unroll
    for (int ntl = 0; ntl < 4; ++ntl) {
      const bf16x8 afr = ((const bf16x8*)encswz)[(ntb[ntl] * 8 + ks) * 64 + lane];
      #pragma unroll
      for (int st = 0; st < 4; ++st)
        acc[ntl][st] = __builtin_amdgcn_mfma_f32_16x16x32_bf16(
            afr, bfr[st], acc[ntl][st], 0, 0, 0);
    }
  }

  const int nbase = (b * 64 + h) * 64;
  #pragma unroll
  for (int ntl = 0; ntl < 2; ++ntl) {
    const int d0 = ntb[ntl] * 16 + lgrp * 4;    // <128
    #pragma unroll
    for (int st = 0; st < 4; ++st) {
      const int site = st * 16 + lrow;
      const float m = mean_s[site], rs = rstd_s[site];
      #pragma unroll
      for (int j = 0; j < 4; ++j) {
        const int d = d0 + j;
        const float xer = rs * acc[ntl][st][j] - rs * m * evec[d] + cvec[d];
        const float xei = rs * acc[ntl + 2][st][j] - rs * m * evec[d + 128] + cvec[d + 128];
        const float sr = tanh_fast(xer) * gain_s[d];
        const float si = tanh_fast(xei) * gain_s[d];
        const float vr = xer + sr, vi = xei + si;
        const float ur = vr * fre_s[d] - vi * fim_s[d];
        const float ui = vr * fim_s[d] + vi * fre_s[d];
        u32[(size_t)t * ND_ + (size_t)d * N_ + nbase + site] = cvt_pk(ur, ui);
      }
    }
  }
}

// ---------------- kernel 4: sequential scan over T (in place, packed bf16, uint2/thread) ----------------

__global__ __launch_bounds__(256) void k_scan(
    uint2* __restrict__ u64p, const float4* __restrict__ decay) {
  const int gidx = blockIdx.x * 256 + threadIdx.x;   // 0..ND/2
  const int flat = gidx * 2;                          // d*N + n (even)
  const int n = flat & 8191;
  const int d = flat >> 13;
  const int b = n >> 12;
  float h0r = 0.f, h0i = 0.f, h1r = 0.f, h1i = 0.f;
  #pragma unroll
  for (int t = 0; t < 16; ++t) {
    const float4 dc = decay[(b * 16 + t) * 128 + d];   // wave-uniform
    const size_t off = ((size_t)t * ND_ + flat) >> 1;  // uint2 units
    uint2 v = u64p[off];
    {
      const float ur = __uint_as_float(v.x << 16);
      const float ui = __uint_as_float(v.x & 0xffff0000u);
      const float nr = fmaf(dc.x, h0r, fmaf(-dc.y, h0i, ur));
      const float ni = fmaf(dc.x, h0i, fmaf(dc.y, h0r, ui));
      h0r = nr; h0i = ni;
      v.x = cvt_pk(h0r, h0i);
    }
    {
      const float ur = __uint_as_float(v.y << 16);
      const float ui = __uint_as_float(v.y & 0xffff0000u);
      const float nr = fmaf(dc.x, h1r, fmaf(-dc.y, h1i, ur));
      const float ni = fmaf(dc.x, h1i, fmaf(dc.y, h1r, ui));
      h1r = nr; h1i = ni;
      v.y = cvt_pk(h1r, h1i);
    }
    u64p[off] = v;
  }
}

// ---------------- kernel 6: drift-decode (fused) + complex FFN via bf16 MFMA ----------------

__global__ __launch_bounds__(256, 2) void k_ffn_mfma(
    const uint* __restrict__ x2p, const uint* __restrict__ h32,
    const ushort* __restrict__ decswz,
    const ushort* __restrict__ b1swz, const ushort* __restrict__ b2swz,
    const float* __restrict__ b1_re, const float* __restrict__ b1_im,
    const float* __restrict__ b2_re, const float* __restrict__ b2_im,
    float* __restrict__ out) {
  __shared__ ushort xlds[64][256];
  __shared__ ushort actlds[2][64][136];
  const int tid = threadIdx.x;
  const int wave = tid >> 6, lane = tid & 63;
  const int lrow = lane & 15, lgrp = lane >> 4;
  const int blk = blockIdx.x;        // 2048 = bt*64 + h
  const int bt = blk >> 6;
  const int hrow = blk & 63;
  const int hw0 = hrow * 64;
  const int b = bt >> 4, t = bt & 15;
  const int nbase = (b * 64 + hrow) * 64;
  const bf16x8* b1f = (const bf16x8*)b1swz;
  const bf16x8* b2f = (const bf16x8*)b2swz;
  const bf16x8* dcf = (const bf16x8*)decswz;
  ushort* hbuf = &actlds[0][0][0];   // [64 site][264 pad] view, dead before chunk 0

  // stage x2 (packed, pass-through) and h (packed)
  #pragma unroll
  for (int i = 0; i < 8; ++i) {
    const int q = i * 4 + wave;        // d-quad 0..31
    const uint* src = &x2p[((size_t)bt * D_ + q * 4) * HW_ + hw0 + lane];
    uint4 u;
    u.x = src[0]; u.y = src[HW_]; u.z = src[2 * HW_]; u.w = src[3 * HW_];
    *(uint4*)&xlds[lane][(q ^ (lane & 7)) << 3] = u;
  }
  #pragma unroll
  for (int i = 0; i < 8; ++i) {
    const int q = i * 4 + wave;
    const size_t o = (size_t)t * ND_ + (size_t)(q * 4) * N_ + nbase + lane;
    uint4 u;
    u.x = h32[o]; u.y = h32[o + N_]; u.z = h32[o + 2 * N_]; u.w = h32[o + 3 * N_];
    *(uint4*)&hbuf[lane * 264 + ((q ^ (lane & 7)) << 3)] = u;
  }

  // prefetch chunk-0 A-fragments
  bf16x8 a1[2][8];
  #pragma unroll
  for (int ntl = 0; ntl < 2; ++ntl)
    #pragma unroll
    for (int ks = 0; ks < 8; ++ks)
      a1[ntl][ks] = b1f[((wave * 2 + ntl) * 8 + ks) * 64 + lane];
  bf16x8 a2[4][2];
  #pragma unroll
  for (int rt = 0; rt < 4; ++rt)
    #pragma unroll
    for (int k2 = 0; k2 < 2; ++k2)
      a2[rt][k2] = b2f[((wave * 4 + rt) * 32 + k2) * 64 + lane];

  __syncthreads();
  const int swz = lrow & 7;

  // ---- fused decode: drift = h @ decP (real), RMW into xlds re-halves
  {
    f32x4 dr[2][4];
    #pragma unroll
    for (int ntl = 0; ntl < 2; ++ntl)
      #pragma unroll
      for (int st = 0; st < 4; ++st) dr[ntl][st] = (f32x4)0.f;
    #pragma unroll
    for (int ks = 0; ks < 8; ++ks) {
      bf16x8 bfr[4];
      #pragma unroll
      for (int st = 0; st < 4; ++st)
        bfr[st] = *(const bf16x8*)&hbuf[(st * 16 + lrow) * 264
                                        + (((ks * 4 + lgrp) ^ swz) << 3)];
      #pragma unroll
      for (int ntl = 0; ntl < 2; ++ntl) {
        const bf16x8 afr = dcf[((wave * 2 + ntl) * 8 + ks) * 64 + lane];
        #pragma unroll
        for (int st = 0; st < 4; ++st)
          dr[ntl][st] = __builtin_amdgcn_mfma_f32_16x16x32_bf16(
              afr, bfr[st], dr[ntl][st], 0, 0, 0);
      }
    }
    #pragma unroll
    for (int ntl = 0; ntl < 2; ++ntl) {
      #pragma unroll
      for (int st = 0; st < 4; ++st) {
        const int site = st * 16 + lrow;
        #pragma unroll
        for (int j = 0; j < 4; ++j) {
          const int d = (wave * 2 + ntl) * 16 + lgrp * 4 + j;
          ushort* p = &xlds[site][(((d >> 2) ^ (site & 7)) << 3) + (d & 3) * 2];
          const uint v = *(uint*)p;
          const float re = __uint_as_float(v << 16) + dr[ntl][st][j];
          *(uint*)p = (v & 0xffff0000u) | (uint)f2bf(re);
        }
      }
    }
  }
  __syncthreads();   // xlds now holds x3; hbuf (actlds) free

  f32x4 dacc[4][4];
  #pragma unroll
  for (int rt = 0; rt < 4; ++rt)
    #pragma unroll
    for (int st = 0; st < 4; ++st) dacc[rt][st] = (f32x4)0.f;

  for (int chunk = 0; chunk < 8; ++chunk) {
    const int nc = (chunk + 1) & 7;

    // ---- GEMM1(chunk)
    f32x4 hacc[2][4];
    #pragma unroll
    for (int ntl = 0; ntl < 2; ++ntl)
      #pragma unroll
      for (int st = 0; st < 4; ++st) hacc[ntl][st] = (f32x4)0.f;

    #pragma unroll
    for (int ks = 0; ks < 8; ++ks) {
      bf16x8 bfr[4];
      #pragma unroll
      for (int st = 0; st < 4; ++st)
        bfr[st] = *(const bf16x8*)&xlds[st * 16 + lrow][(((ks * 4 + lgrp) ^ swz)) << 3];
      #pragma unroll
      for (int ntl = 0; ntl < 2; ++ntl)
        #pragma unroll
        for (int st = 0; st < 4; ++st)
          hacc[ntl][st] = __builtin_amdgcn_mfma_f32_16x16x32_bf16(
              a1[ntl][ks], bfr[st], hacc[ntl][st], 0, 0, 0);
    }

    // ---- prefetch a1 for next chunk
    #pragma unroll
    for (int ntl = 0; ntl < 2; ++ntl)
      #pragma unroll
      for (int ks = 0; ks < 8; ++ks)
        a1[ntl][ks] = b1f[((nc * 8 + wave * 2 + ntl) * 8 + ks) * 64 + lane];

    // ---- bias + gelu -> act[chunk&1]
    uint* act32 = (uint*)&actlds[chunk & 1][0][0];
    #pragma unroll
    for (int ntl = 0; ntl < 2; ++ntl) {
      const int nlocal0 = (wave * 2 + ntl) * 16 + lgrp * 4;
      const int ng0 = chunk * 128 + nlocal0;
      #pragma unroll
      for (int st = 0; st < 4; ++st) {
        float gv[4];
        #pragma unroll
        for (int j = 0; j < 4; ++j) {
          const int ng = ng0 + j;
          const float bias = (ng < 512) ? b1_re[ng] : b1_im[ng - 512];
          gv[j] = gelu_fast(hacc[ntl][st][j] + bias);
        }
        const int site = st * 16 + lrow;
        act32[site * 68 + (nlocal0 >> 1)] = cvt_pk(gv[0], gv[1]);
        act32[site * 68 + (nlocal0 >> 1) + 1] = cvt_pk(gv[2], gv[3]);
      }
    }

    // ---- load this chunk's GEMM2 ks2 2-3 frags
    bf16x8 a2b[4][2];
    #pragma unroll
    for (int rt = 0; rt < 4; ++rt)
      #pragma unroll
      for (int k2 = 0; k2 < 2; ++k2)
        a2b[rt][k2] = b2f[((wave * 4 + rt) * 32 + chunk * 4 + 2 + k2) * 64 + lane];

    __syncthreads();   // act[chunk&1] ready (one barrier/chunk)

    // ---- GEMM2(chunk)
    const ushort* actb = &actlds[chunk & 1][0][0];
    #pragma unroll
    for (int ks2 = 0; ks2 < 2; ++ks2) {
      bf16x8 bfr[4];
      #pragma unroll
      for (int st = 0; st < 4; ++st)
        bfr[st] = *(const bf16x8*)&actb[(st * 16 + lrow) * 136 + ks2 * 32 + lgrp * 8];
      #pragma unroll
      for (int rt = 0; rt < 4; ++rt)
        #pragma unroll
        for (int st = 0; st < 4; ++st)
          dacc[rt][st] = __builtin_amdgcn_mfma_f32_16x16x32_bf16(
              a2[rt][ks2], bfr[st], dacc[rt][st], 0, 0, 0);
    }
    #pragma unroll
    for (int ks2 = 0; ks2 < 2; ++ks2) {
      bf16x8 bfr[4];
      #pragma unroll
      for (int st = 0; st < 4; ++st)
        bfr[st] = *(const bf16x8*)&actb[(st * 16 + lrow) * 136 + (ks2 + 2) * 32 + lgrp * 8];
      #pragma unroll
      for (int rt = 0; rt < 4; ++rt)
        #pragma unroll
        for (int st = 0; st < 4; ++st)
          dacc[rt][st] = __builtin_amdgcn_mfma_f32_16x16x32_bf16(
              a2b[rt][ks2], bfr[st], dacc[rt][st], 0, 0, 0);
    }

    // ---- prefetch next chunk's GEMM2 ks2 0-1 frags
    #pragma unroll
    for (int rt = 0; rt < 4; ++rt)
      #pragma unroll
      for (int k2 = 0; k2 < 2; ++k2)
        a2[rt][k2] = b2f[((wave * 4 + rt) * 32 + nc * 4 + k2) * 64 + lane];
  }

  // epilogue: residual x3 from xlds, bias2, interleaved [.,2] output
  #pragma unroll
  for (int rt = 0; rt < 4; ++rt) {
    #pragma unroll
    for (int j = 0; j < 4; ++j) {
      const int n2 = (wave * 4 + rt) * 16 + lgrp * 4 + j;
      const int d = n2 & 127;
      const int c = n2 >> 7;
      const float bias2 = c ? b2_im[d] : b2_re[d];
      #pragma unroll
      for (int st = 0; st < 4; ++st) {
        const int site = st * 16 + lrow;
        const uint pr = *(const uint*)&xlds[site][(((d >> 2) ^ (site & 7)) << 3)
                                                  + (d & 3) * 2];
        const float rv = c ? __uint_as_float(pr & 0xffff0000u)
                           : __uint_as_float(pr << 16);
        const size_t idx = (size_t)(bt * D_ + d) * HW_ + hw0 + site;
        out[idx * 2 + c] = rv + dacc[rt][st][j] + bias2;
      }
    }
  }
}

// ---------------- host launcher ----------------

extern "C" void kernel_launch(void* const* d_in, const int* in_sizes, int n_in,
                              void* d_out, int out_size, void* d_ws, size_t ws_size,
                              hipStream_t stream) {
  const float* x_re   = (const float*)d_in[0];
  const float* x_im   = (const float*)d_in[1];
  const float* dt     = (const float*)d_in[2];
  const float* ln_s_g = (const float*)d_in[3];
  const float* ln_s_b = (const float*)d_in[4];
  const float* ln_t_g = (const float*)d_in[5];
  const float* ln_t_b = (const float*)d_in[6];
  const float* metric = (const float*)d_in[7];
  const float* conv_w = (const float*)d_in[8];
  const float* conv_b = (const float*)d_in[9];
  const float* nu     = (const float*)d_in[10];
  const float* theta  = (const float*)d_in[11];
  const float* enc_re = (const float*)d_in[12];
  const float* enc_im = (const float*)d_in[13];
  const float* dec_re = (const float*)d_in[14];
  const float* dec_im = (const float*)d_in[15];
  const float* src_g  = (const float*)d_in[16];
  const float* w1_re  = (const float*)d_in[17];
  const float* w1_im  = (const float*)d_in[18];
  const float* b1_re  = (const float*)d_in[19];
  const float* b1_im  = (const float*)d_in[20];
  const float* w2_re  = (const float*)d_in[21];
  const float* w2_im  = (const float*)d_in[22];
  const float* b2_re  = (const float*)d_in[23];
  const float* b2_im  = (const float*)d_in[24];
  float* out = (float*)d_out;
  float* ws = (float*)d_ws;

  // prep region (non-aliased: all weights prepped once, up front)
  ushort* wt16   = (ushort*)ws;
  ushort* cwswz  = wt16;                     // 589,824 ushorts
  ushort* b1swz  = wt16 + 589824;            // 262,144
  ushort* b2swz  = wt16 + 851968;            // 262,144
  ushort* encswz = wt16 + 1114112;           // 65,536
  ushort* decswz = wt16 + 1179648;           // 32,768
  float*  evec   = (float*)(wt16 + 1212416); // 256
  float*  cvec   = evec + 256;               // 256
  float4* decay  = (float4*)(cvec + 256);    // 4096 float4 (64 KB)
  float*  bufA   = ws + PREP_FLOATS;
  ushort* xri_bf = (ushort*)bufA;            // 67 MB (dead after conv)

  // planA: xri | u32(+128KB skew over xri) | x2p(+256KB skew) | xp(+512KB skew)
  const size_t needA = ((size_t)PREP_FLOATS + 3 * (size_t)PLANE_) * 4 + (2u << 20);
  const bool planA = ws_size >= needA;
  uint *u32p, *x2p, *xp;
  float* ffn_out;
  if (planA) {
    u32p = (uint*)bufA + 32768;                      // overwrites dead xri (skewed)
    x2p  = (uint*)bufA + PLANE_ + 65536;
    xp   = (uint*)bufA + 2 * (size_t)PLANE_ + 131072;
    ffn_out = out;
  } else {
    // route u32/x2p through d_out; xp in ws after xri; final d2d copy
    u32p = (uint*)out;
    x2p  = (uint*)out + PLANE_;
    xp   = (uint*)bufA + PLANE_;
    ffn_out = bufA;
  }

  k_prep_all<<<609, 256, 0, stream>>>(conv_w, dt, nu, theta, w1_re, w1_im,
                                      w2_re, w2_im, enc_re, enc_im, dec_re, dec_im,
                                      ln_t_g, ln_t_b,
                                      cwswz, decay, b1swz, b2swz, encswz, decswz,
                                      evec, cvec);
  k_spatial_ln<<<BT_ * H_, 256, 0, stream>>>(x_re, x_im, ln_s_g, ln_s_b, metric,
                                             xri_bf, xp);
  k_conv_mfma<<<BT_ * 32, 512, 0, stream>>>(xri_bf, cwswz, conv_b, xp, x2p);
  k_temporal_mfma<<<B_ * T_ * H_, 256, 0, stream>>>(x2p, encswz, evec, cvec,
                                                    decay, src_g, u32p);
  k_scan<<<ND_ / 512, 256, 0, stream>>>((uint2*)u32p, decay);
  k_ffn_mfma<<<BT_ * H_, 256, 0, stream>>>(x2p, u32p, decswz, b1swz, b2swz,
                                           b1_re, b1_im, b2_re, b2_im, ffn_out);
  if (!planA) {
    hipMemcpyAsync(d_out, ffn_out, (size_t)2 * PLANE_ * sizeof(float),
                   hipMemcpyDeviceToDevice, stream);
  }
}

// Round 15
// 641.520 us; speedup vs baseline: 1.0535x; 1.0253x over previous
//
#include <hip/hip_runtime.h>
#include <hip/hip_bf16.h>
#include <stdint.h>

#define B_   2
#define T_   16
#define D_   128
#define D2_  256
#define H_   64
#define W_   64
#define HW_  4096
#define BT_  32
#define N_   8192
#define ND_  1048576           // N_*D_
#define PLANE_ 16777216        // B*T*D*H*W  (one of re/im)
#define PREP_FLOATS 655360     // prep region: 2.5 MB

typedef short bf16x8 __attribute__((ext_vector_type(8)));
typedef float f32x4 __attribute__((ext_vector_type(4)));
typedef unsigned int uint;
typedef unsigned short ushort;

// ---------------- device helpers ----------------

__device__ __forceinline__ float softplus_f(float x) {
  return fmaxf(x, 0.0f) + log1pf(expf(-fabsf(x)));
}

__device__ __forceinline__ float gelu_fast(float x) {
  const float Ac = 2.3022082963f;   // 2*sqrt(2/pi)*log2(e)
  const float Bc = 0.1029437f;      // Ac*0.044715
  float t = x * x;
  float z = x * fmaf(Bc, t, Ac);
  float e = __builtin_amdgcn_exp2f(z);
  float r = __builtin_amdgcn_rcpf(e + 1.0f);
  return fmaf(-x, r, x);
}

__device__ __forceinline__ float tanh_fast(float x) {
  float e = __builtin_amdgcn_exp2f(x * 2.8853900818f);  // 2*log2(e)
  float r = __builtin_amdgcn_rcpf(e + 1.0f);
  return fmaf(-2.0f, r, 1.0f);
}

__device__ __forceinline__ ushort f2bf(float f) {
  uint u = __float_as_uint(f);
  uint r = (u + 0x7fffu + ((u >> 16) & 1u)) >> 16;   // RNE
  return (ushort)r;
}

__device__ __forceinline__ uint cvt_pk(float a, float b) {
  __hip_bfloat162 h = __float22bfloat162_rn(make_float2(a, b));
  return *reinterpret_cast<uint*>(&h);
}

__device__ __forceinline__ uint4 pack8(const ushort v[8]) {
  uint4 u;
  u.x = (uint)v[0] | ((uint)v[1] << 16);
  u.y = (uint)v[2] | ((uint)v[3] << 16);
  u.z = (uint)v[4] | ((uint)v[5] << 16);
  u.w = (uint)v[6] | ((uint)v[7] << 16);
  return u;
}

// ---------------- kernel 0: ALL weight prep in one launch ----------------
// blocks [0,288): conv frags | [288,304): decay | [304,432): b1 | [432,560): b2
// [560,592): enc | [592,593): encvec | [593,609): dec

__global__ __launch_bounds__(256) void k_prep_all(
    const float* __restrict__ wg,
    const float* __restrict__ dt, const float* __restrict__ nu,
    const float* __restrict__ theta,
    const float* __restrict__ w1_re, const float* __restrict__ w1_im,
    const float* __restrict__ w2_re, const float* __restrict__ w2_im,
    const float* __restrict__ enc_re, const float* __restrict__ enc_im,
    const float* __restrict__ dec_re, const float* __restrict__ dec_im,
    const float* __restrict__ g, const float* __restrict__ bb,
    ushort* __restrict__ cwswz, float4* __restrict__ decay,
    ushort* __restrict__ b1swz, ushort* __restrict__ b2swz,
    ushort* __restrict__ encswz, ushort* __restrict__ decswz,
    float* __restrict__ evec, float* __restrict__ cvec) {
  const int blk = blockIdx.x;
  const int tid = threadIdx.x;

  if (blk < 288) {                       // ---- conv frags (remapped tile order)
    const int t = blk * 256 + tid;
    if (t >= 73728) return;
    const int lane = t & 63;
    const int nt = (t >> 6) & 15;
    const int ks = (t >> 10) & 7;
    const int kk = t >> 13;
    const int cwv = nt >> 2, jjv = nt & 3;
    const int co_tile = (jjv < 2) ? (2 * cwv + jjv) : (8 + 2 * cwv + (jjv - 2));
    const int co = co_tile * 16 + (lane & 15);
    const int ci0 = ks * 32 + (lane >> 4) * 8;
    ushort v[8];
    #pragma unroll
    for (int e = 0; e < 8; ++e)
      v[e] = f2bf(wg[((size_t)co * 256 + ci0 + e) * 9 + kk]);
    ((uint4*)cwswz)[t] = pack8(v);
  } else if (blk < 304) {                // ---- decay/forcing table
    const int idx = (blk - 288) * 256 + tid;
    const int d = idx & 127;
    const int bt = idx >> 7;
    const float dtv = dt[bt];
    const float lr = -softplus_f(nu[d]);
    const float li = theta[d];
    float s, c;
    sincosf(li * dtv, &s, &c);
    const float er = expf(lr * dtv);
    const float ar = er * c, ai = er * s;
    const float den = lr * lr + li * li;
    const float nr = ar - 1.f, ni = ai;
    float4 v;
    v.x = ar; v.y = ai;
    v.z = (nr * lr + ni * li) / den;
    v.w = (ni * lr - nr * li) / den;
    decay[idx] = v;
  } else if (blk < 432) {                // ---- FFN B1 frags (k-permuted)
    const int t = (blk - 304) * 256 + tid;
    const int lane = t & 63;
    const int ks = (t >> 6) & 7;
    const int ntile = t >> 9;
    const int n = ntile * 16 + (lane & 15);
    const int k0 = ks * 32 + (lane >> 4) * 8;
    ushort v[8];
    #pragma unroll
    for (int e = 0; e < 8; ++e) {
      const int kp = k0 + e;
      const int k = (kp >> 1) | ((kp & 1) << 7);
      float val;
      if (k < 128) {
        val = (n < 512) ? w1_re[k * 512 + n] : w1_im[k * 512 + (n - 512)];
      } else {
        const int kk = k - 128;
        val = (n < 512) ? -w1_im[kk * 512 + n] : w1_re[kk * 512 + (n - 512)];
      }
      v[e] = f2bf(val);
    }
    ((uint4*)b1swz)[t] = pack8(v);
  } else if (blk < 560) {                // ---- FFN B2 frags
    const int t = (blk - 432) * 256 + tid;
    const int lane = t & 63;
    const int kc = (t >> 6) & 31;
    const int rowtile = t >> 11;
    const int n2 = rowtile * 16 + (lane & 15);
    const int k0 = kc * 32 + (lane >> 4) * 8;
    ushort v[8];
    #pragma unroll
    for (int e = 0; e < 8; ++e) {
      const int k = k0 + e;
      float val;
      if (k < 512) {
        val = (n2 < 128) ? w2_re[k * 128 + n2] : w2_im[k * 128 + (n2 - 128)];
      } else {
        const int kk = k - 512;
        val = (n2 < 128) ? -w2_im[kk * 128 + n2] : w2_re[kk * 128 + (n2 - 128)];
      }
      v[e] = f2bf(val);
    }
    ((uint4*)b2swz)[t] = pack8(v);
  } else if (blk < 592) {                // ---- enc frags (g-scaled, k-permuted)
    const int t = (blk - 560) * 256 + tid;
    const int lane = t & 63;
    const int ks = (t >> 6) & 7;
    const int ntile = t >> 9;
    const int n = ntile * 16 + (lane & 15);
    const int k0 = ks * 32 + (lane >> 4) * 8;
    ushort v[8];
    #pragma unroll
    for (int e = 0; e < 8; ++e) {
      const int kp = k0 + e;
      const int k = (kp >> 1) | ((kp & 1) << 7);
      float val;
      if (k < 128) {
        val = (n < 128) ? enc_re[k * 128 + n] : enc_im[k * 128 + (n - 128)];
      } else {
        const int kk = k - 128;
        val = (n < 128) ? -enc_im[kk * 128 + n] : enc_re[kk * 128 + (n - 128)];
      }
      v[e] = f2bf(val * g[k]);
    }
    ((uint4*)encswz)[t] = pack8(v);
  } else if (blk < 593) {                // ---- evec/cvec
    const int n = tid;
    float se = 0.f, sc = 0.f;
    for (int k = 0; k < 256; ++k) {
      float ep;
      if (k < 128) {
        ep = (n < 128) ? enc_re[k * 128 + n] : enc_im[k * 128 + (n - 128)];
      } else {
        const int kk = k - 128;
        ep = (n < 128) ? -enc_im[kk * 128 + n] : enc_re[kk * 128 + (n - 128)];
      }
      se = fmaf(g[k], ep, se);
      sc = fmaf(bb[k], ep, sc);
    }
    evec[n] = se;
    cvec[n] = sc;
  } else {                               // ---- dec frags (real-part, k-permuted)
    const int t = (blk - 593) * 256 + tid;
    const int lane = t & 63;
    const int ks = (t >> 6) & 7;
    const int ntile = t >> 9;
    const int n = ntile * 16 + (lane & 15);
    const int k0 = ks * 32 + (lane >> 4) * 8;
    ushort v[8];
    #pragma unroll
    for (int e = 0; e < 8; ++e) {
      const int kp = k0 + e;
      const int k = (kp >> 1) | ((kp & 1) << 7);
      float val = (k < 128) ? dec_re[k * 128 + n] : -dec_im[(k - 128) * 128 + n];
      v[e] = f2bf(val);
    }
    ((uint4*)decswz)[t] = pack8(v);
  }
}

// ---------------- kernel 1: spatial complex LN + metric -> xri bf16 [BT][H][32u][64w][8ci]
//                  + packed raw residual xp [BT][128][HW] (re,im bf16) ----------------

__global__ __launch_bounds__(256) void k_spatial_ln(
    const float* __restrict__ x_re, const float* __restrict__ x_im,
    const float* __restrict__ g, const float* __restrict__ bb,
    const float* __restrict__ metric, ushort* __restrict__ xri,
    uint* __restrict__ xp) {
  __shared__ float vals[256][64];
  __shared__ float red1[4][64];
  __shared__ float red2[4][64];
  __shared__ float mean_s[64];
  __shared__ float rstd_s[64];
  const int blk = blockIdx.x;      // bt*64 + h
  const int bt = blk >> 6;
  const int h = blk & 63;
  const int tid = threadIdx.x;
  const int w = tid & 63, q = tid >> 6;

  const float* src = (q < 2) ? x_re : x_im;   // wave-uniform
  float s1 = 0.f, s2 = 0.f;
  #pragma unroll 4
  for (int i = 0; i < 64; ++i) {
    const int c = q * 64 + i;
    const int d = c & 127;
    float v = src[((size_t)bt * D_ + d) * HW_ + h * W_ + w];
    vals[c][w] = v;
    s1 += v; s2 += v * v;
  }
  red1[q][w] = s1; red2[q][w] = s2;
  __syncthreads();
  if (tid < 64) {
    float m = red1[0][tid] + red1[1][tid] + red1[2][tid] + red1[3][tid];
    float ss = red2[0][tid] + red2[1][tid] + red2[2][tid] + red2[3][tid];
    m *= (1.f / 256.f);
    float var = ss * (1.f / 256.f) - m * m;
    mean_s[tid] = m;
    rstd_s[tid] = rsqrtf(var + 1e-5f);
  }
  __syncthreads();
  // packed raw residual: all 256 threads, 32 d's each
  #pragma unroll
  for (int i = 0; i < 32; ++i) {
    const int d = q * 32 + i;
    xp[((size_t)bt * D_ + d) * HW_ + h * W_ + w] =
        cvt_pk(vals[d][w], vals[d + 128][w]);
  }
  const float m = mean_s[w], rs = rstd_s[w];
  const size_t ubase = (((size_t)bt * 64 + h) * 32 + q * 8) * 512 + w * 8;
  #pragma unroll
  for (int j = 0; j < 8; ++j) {
    uint4 u;
    #pragma unroll
    for (int e2 = 0; e2 < 4; ++e2) {
      const int c0 = q * 64 + j * 8 + e2 * 2;
      float v0 = (vals[c0][w] - m) * rs * g[c0] + bb[c0];
      v0 *= metric[(size_t)c0 * HW_ + h * W_ + w];
      float v1 = (vals[c0 + 1][w] - m) * rs * g[c0 + 1] + bb[c0 + 1];
      v1 *= metric[(size_t)(c0 + 1) * HW_ + h * W_ + w];
      ((uint*)&u)[e2] = cvt_pk(v0, v1);
    }
    *(uint4*)&xri[ubase + (size_t)j * 512] = u;
  }
}

// ---------------- kernel 2: 3x3 conv via bf16 MFMA -> x2p packed bf16 [BT][128][HW] ----------------
// Half-split staging (66 KB LDS, launch_bounds(512,4), r11-verified config);
// wave-local pack epilogue with packed bf16 residual from xp.

__global__ __launch_bounds__(512, 4) void k_conv_mfma(
    const ushort* __restrict__ xri, const ushort* __restrict__ cwswz,
    const float* __restrict__ bias,
    const uint* __restrict__ xp,
    uint* __restrict__ x2p) {
  __shared__ ushort xb[33792];   // 4 rows * 16 units * 66 w * 8 ci = 66 KB
  const int tid = threadIdx.x;
  const int wave = tid >> 6, lane = tid & 63;
  const int lrow = lane & 15, lgrp = lane >> 4;
  const int blk = blockIdx.x;         // 1024 = bt*32 + hp
  const int bt = blk >> 5;
  const int h0 = (blk & 31) * 2;
  const int cw = wave & 3;
  const int sg = wave >> 2;

  f32x4 acc[4][4];
  #pragma unroll
  for (int j = 0; j < 4; ++j)
    #pragma unroll
    for (int i = 0; i < 4; ++i) acc[j][i] = (f32x4)0.f;

  for (int half = 0; half < 2; ++half) {
    __syncthreads();   // protect previous half's reads
    // zero halo (w slots 0 and 65)
    if (tid < 128) {
      const int j = tid >> 5;
      const int u = (tid >> 1) & 15;
      const int wz = (tid & 1) * 65;
      uint4 z = {0u, 0u, 0u, 0u};
      *(uint4*)&xb[((j * 16 + u) * 66 + wz) * 8] = z;
    }
    // coalesced staging: 8 iters x uint4
    #pragma unroll
    for (int i = 0; i < 8; ++i) {
      const int idx = i * 512 + tid;    // 0..4095
      const int w = idx & 63;
      const int u = (idx >> 6) & 15;
      const int j = idx >> 10;          // row 0..3
      const int hh = h0 + j - 1;
      uint4 v = {0u, 0u, 0u, 0u};
      if (hh >= 0 && hh < 64)
        v = *(const uint4*)&xri[(((size_t)bt * 64 + hh) * 32 + half * 16 + u) * 512
                                + w * 8];
      *(uint4*)&xb[((j * 16 + u) * 66 + 1 + w) * 8] = v;
    }
    __syncthreads();

    for (int kh = 0; kh < 3; ++kh) {
      for (int kw = 0; kw < 3; ++kw) {
        const int kk = kh * 3 + kw;
        #pragma unroll
        for (int ks = 0; ks < 4; ++ks) {
          bf16x8 bfr[4];
          #pragma unroll
          for (int i = 0; i < 4; ++i)
            bfr[i] = *(const bf16x8*)&xb[(((sg + kh) * 16 + ks * 4 + lgrp) * 66
                                          + i * 16 + lrow + kw) * 8];
          const int fbase = ((kk * 8 + half * 4 + ks) * 16 + cw * 4) * 64 + lane;
          #pragma unroll
          for (int j = 0; j < 4; ++j) {
            const bf16x8 afr = ((const bf16x8*)cwswz)[fbase + j * 64];
            #pragma unroll
            for (int i = 0; i < 4; ++i)
              acc[j][i] = __builtin_amdgcn_mfma_f32_16x16x32_bf16(
                  afr, bfr[i], acc[j][i], 0, 0, 0);
          }
        }
      }
    }
  }

  // ---- epilogue: wave-local pack (re = acc[j], im = acc[j+2], same d), bf16 residual
  #pragma unroll
  for (int j = 0; j < 2; ++j) {
    #pragma unroll
    for (int jj = 0; jj < 4; ++jj) {
      const int d = (2 * cw + j) * 16 + lgrp * 4 + jj;   // 0..127
      const float bvr = bias[d];
      const float bvi = bias[d + 128];
      const size_t rowoff = ((size_t)bt * D_ + d) * HW_ + (h0 + sg) * W_;
      #pragma unroll
      for (int i = 0; i < 4; ++i) {
        const int w = i * 16 + lrow;
        const uint xv = xp[rowoff + w];
        const float re = acc[j][i][jj] + bvr + __uint_as_float(xv << 16);
        const float im = acc[j + 2][i][jj] + bvi + __uint_as_float(xv & 0xffff0000u);
        x2p[rowoff + w] = cvt_pk(re, im);
      }
    }
  }
}

// ---------------- kernel 3: temporal LN (folded) + encode MFMA + src + ZOH -> u32 [T][D][N] ----------------

__global__ __launch_bounds__(256, 2) void k_temporal_mfma(
    const uint* __restrict__ x2p,
    const ushort* __restrict__ encswz,
    const float* __restrict__ evec, const float* __restrict__ cvec,
    const float4* __restrict__ decay,
    const float* __restrict__ src_gain,
    uint* __restrict__ u32) {
  __shared__ ushort xlds[64][256];
  __shared__ float red1[4][64], red2[4][64];
  __shared__ float mean_s[64], rstd_s[64];
  __shared__ float fre_s[128], fim_s[128], gain_s[128];
  const int tid = threadIdx.x;
  const int wave = tid >> 6, lane = tid & 63;
  const int lrow = lane & 15, lgrp = lane >> 4;
  const int blk = blockIdx.x;          // ((b*16)+t)*64 + h
  const int h = blk & 63;
  const int t = (blk >> 6) & 15;
  const int b = blk >> 10;
  const int bt = b * T_ + t;

  // stage packed x2 -> LDS (pass-through) + LN sums
  float s1 = 0.f, s2 = 0.f;
  #pragma unroll
  for (int i = 0; i < 8; ++i) {
    const int q = i * 4 + wave;        // d-quad 0..31
    const uint* src = &x2p[((size_t)bt * D_ + q * 4) * HW_ + h * W_ + lane];
    uint4 u;
    u.x = src[0];
    u.y = src[HW_];
    u.z = src[2 * HW_];
    u.w = src[3 * HW_];
    *(uint4*)&xlds[lane][(q ^ (lane & 7)) << 3] = u;
    #pragma unroll
    for (int e = 0; e < 4; ++e) {
      const uint v = ((const uint*)&u)[e];
      const float re = __uint_as_float(v << 16);
      const float im = __uint_as_float(v & 0xffff0000u);
      s1 += re + im;
      s2 += re * re + im * im;
    }
  }
  red1[wave][lane] = s1;
  red2[wave][lane] = s2;
  __syncthreads();
  if (tid < 64) {
    float m = red1[0][tid] + red1[1][tid] + red1[2][tid] + red1[3][tid];
    float ss = red2[0][tid] + red2[1][tid] + red2[2][tid] + red2[3][tid];
    m *= (1.f / 256.f);
    float var = ss * (1.f / 256.f) - m * m;
    mean_s[tid] = m;
    rstd_s[tid] = rsqrtf(var + 1e-5f);
  }
  if (tid < 128) {
    const float4 dc = decay[bt * 128 + tid];
    fre_s[tid] = dc.z;
    fim_s[tid] = dc.w;
    gain_s[tid] = src_gain[tid];
  }
  __syncthreads();

  f32x4 acc[4][4];
  #pragma unroll
  for (int ntl = 0; ntl < 4; ++ntl)
    #pragma unroll
    for (int st = 0; st < 4; ++st) acc[ntl][st] = (f32x4)0.f;

  const int swz = lrow & 7;
  const int ntb[4] = {wave * 2, wave * 2 + 1, wave * 2 + 8, wave * 2 + 9};
  #pragma unroll
  for (int ks = 0; ks < 8; ++ks) {
    bf16x8 bfr[4];
    #pragma unroll
    for (int st = 0; st < 4; ++st)
      bfr[st] = *(const bf16x8*)&xlds[st * 16 + lrow][(((ks * 4 + lgrp) ^ swz)) << 3];
    #pragma unroll
    for (int ntl = 0; ntl < 4; ++ntl) {
      const bf16x8 afr = ((const bf16x8*)encswz)[(ntb[ntl] * 8 + ks) * 64 + lane];
      #pragma unroll
      for (int st = 0; st < 4; ++st)
        acc[ntl][st] = __builtin_amdgcn_mfma_f32_16x16x32_bf16(
            afr, bfr[st], acc[ntl][st], 0, 0, 0);
    }
  }

  const int nbase = (b * 64 + h) * 64;
  #pragma unroll
  for (int ntl = 0; ntl < 2; ++ntl) {
    const int d0 = ntb[ntl] * 16 + lgrp * 4;    // <128
    #pragma unroll
    for (int st = 0; st < 4; ++st) {
      const int site = st * 16 + lrow;
      const float m = mean_s[site], rs = rstd_s[site];
      #pragma unroll
      for (int j = 0; j < 4; ++j) {
        const int d = d0 + j;
        const float xer = rs * acc[ntl][st][j] - rs * m * evec[d] + cvec[d];
        const float xei = rs * acc[ntl + 2][st][j] - rs * m * evec[d + 128] + cvec[d + 128];
        const float sr = tanh_fast(xer) * gain_s[d];
        const float si = tanh_fast(xei) * gain_s[d];
        const float vr = xer + sr, vi = xei + si;
        const float ur = vr * fre_s[d] - vi * fim_s[d];
        const float ui = vr * fim_s[d] + vi * fre_s[d];
        u32[(size_t)t * ND_ + (size_t)d * N_ + nbase + site] = cvt_pk(ur, ui);
      }
    }
  }
}

// ---------------- kernel 4: sequential scan over T (in place, packed bf16, uint2/thread) ----------------

__global__ __launch_bounds__(256) void k_scan(
    uint2* __restrict__ u64p, const float4* __restrict__ decay) {
  const int gidx = blockIdx.x * 256 + threadIdx.x;   // 0..ND/2
  const int flat = gidx * 2;                          // d*N + n (even)
  const int n = flat & 8191;
  const int d = flat >> 13;
  const int b = n >> 12;
  float h0r = 0.f, h0i = 0.f, h1r = 0.f, h1i = 0.f;
  #pragma unroll
  for (int t = 0; t < 16; ++t) {
    const float4 dc = decay[(b * 16 + t) * 128 + d];   // wave-uniform
    const size_t off = ((size_t)t * ND_ + flat) >> 1;  // uint2 units
    uint2 v = u64p[off];
    {
      const float ur = __uint_as_float(v.x << 16);
      const float ui = __uint_as_float(v.x & 0xffff0000u);
      const float nr = fmaf(dc.x, h0r, fmaf(-dc.y, h0i, ur));
      const float ni = fmaf(dc.x, h0i, fmaf(dc.y, h0r, ui));
      h0r = nr; h0i = ni;
      v.x = cvt_pk(h0r, h0i);
    }
    {
      const float ur = __uint_as_float(v.y << 16);
      const float ui = __uint_as_float(v.y & 0xffff0000u);
      const float nr = fmaf(dc.x, h1r, fmaf(-dc.y, h1i, ur));
      const float ni = fmaf(dc.x, h1i, fmaf(dc.y, h1r, ui));
      h1r = nr; h1i = ni;
      v.y = cvt_pk(h1r, h1i);
    }
    u64p[off] = v;
  }
}

// ---------------- kernel 6: drift-decode (fused) + complex FFN via bf16 MFMA ----------------
// hbuf now uses the xlds-identical [64][256]+XOR layout (was 264-stride: 4-8-way
// bank conflicts on both staging writes and drift reads -> 2.1e7 SQ_LDS_BANK_CONFLICT).

__global__ __launch_bounds__(256, 2) void k_ffn_mfma(
    const uint* __restrict__ x2p, const uint* __restrict__ h32,
    const ushort* __restrict__ decswz,
    const ushort* __restrict__ b1swz, const ushort* __restrict__ b2swz,
    const float* __restrict__ b1_re, const float* __restrict__ b1_im,
    const float* __restrict__ b2_re, const float* __restrict__ b2_im,
    float* __restrict__ out) {
  __shared__ ushort xlds[64][256];
  __shared__ ushort actlds[2][64][136];
  const int tid = threadIdx.x;
  const int wave = tid >> 6, lane = tid & 63;
  const int lrow = lane & 15, lgrp = lane >> 4;
  const int blk = blockIdx.x;        // 2048 = bt*64 + h
  const int bt = blk >> 6;
  const int hrow = blk & 63;
  const int hw0 = hrow * 64;
  const int b = bt >> 4, t = bt & 15;
  const int nbase = (b * 64 + hrow) * 64;
  const bf16x8* b1f = (const bf16x8*)b1swz;
  const bf16x8* b2f = (const bf16x8*)b2swz;
  const bf16x8* dcf = (const bf16x8*)decswz;
  ushort* hbuf = &actlds[0][0][0];   // [64][256] swizzled view (16384 < 17408), dead before chunk 0

  // stage x2 (packed, pass-through) and h (packed)
  #pragma unroll
  for (int i = 0; i < 8; ++i) {
    const int q = i * 4 + wave;        // d-quad 0..31
    const uint* src = &x2p[((size_t)bt * D_ + q * 4) * HW_ + hw0 + lane];
    uint4 u;
    u.x = src[0]; u.y = src[HW_]; u.z = src[2 * HW_]; u.w = src[3 * HW_];
    *(uint4*)&xlds[lane][(q ^ (lane & 7)) << 3] = u;
  }
  #pragma unroll
  for (int i = 0; i < 8; ++i) {
    const int q = i * 4 + wave;
    const size_t o = (size_t)t * ND_ + (size_t)(q * 4) * N_ + nbase + lane;
    uint4 u;
    u.x = h32[o]; u.y = h32[o + N_]; u.z = h32[o + 2 * N_]; u.w = h32[o + 3 * N_];
    *(uint4*)&hbuf[lane * 256 + ((q ^ (lane & 7)) << 3)] = u;
  }

  // prefetch chunk-0 A-fragments
  bf16x8 a1[2][8];
  #pragma unroll
  for (int ntl = 0; ntl < 2; ++ntl)
    #pragma unroll
    for (int ks = 0; ks < 8; ++ks)
      a1[ntl][ks] = b1f[((wave * 2 + ntl) * 8 + ks) * 64 + lane];
  bf16x8 a2[4][2];
  #pragma unroll
  for (int rt = 0; rt < 4; ++rt)
    #pragma unroll
    for (int k2 = 0; k2 < 2; ++k2)
      a2[rt][k2] = b2f[((wave * 4 + rt) * 32 + k2) * 64 + lane];

  __syncthreads();
  const int swz = lrow & 7;

  // ---- fused decode: drift = h @ decP (real), RMW into xlds re-halves
  {
    f32x4 dr[2][4];
    #pragma unroll
    for (int ntl = 0; ntl < 2; ++ntl)
      #pragma unroll
      for (int st = 0; st < 4; ++st) dr[ntl][st] = (f32x4)0.f;
    #pragma unroll
    for (int ks = 0; ks < 8; ++ks) {
      bf16x8 bfr[4];
      #pragma unroll
      for (int st = 0; st < 4; ++st)
        bfr[st] = *(const bf16x8*)&hbuf[(st * 16 + lrow) * 256
                                        + (((ks * 4 + lgrp) ^ swz) << 3)];
      #pragma unroll
      for (int ntl = 0; ntl < 2; ++ntl) {
        const bf16x8 afr = dcf[((wave * 2 + ntl) * 8 + ks) * 64 + lane];
        #pragma unroll
        for (int st = 0; st < 4; ++st)
          dr[ntl][st] = __builtin_amdgcn_mfma_f32_16x16x32_bf16(
              afr, bfr[st], dr[ntl][st], 0, 0, 0);
      }
    }
    #pragma unroll
    for (int ntl = 0; ntl < 2; ++ntl) {
      #pragma unroll
      for (int st = 0; st < 4; ++st) {
        const int site = st * 16 + lrow;
        #pragma unroll
        for (int j = 0; j < 4; ++j) {
          const int d = (wave * 2 + ntl) * 16 + lgrp * 4 + j;
          ushort* p = &xlds[site][(((d >> 2) ^ (site & 7)) << 3) + (d & 3) * 2];
          const uint v = *(uint*)p;
          const float re = __uint_as_float(v << 16) + dr[ntl][st][j];
          *(uint*)p = (v & 0xffff0000u) | (uint)f2bf(re);
        }
      }
    }
  }
  __syncthreads();   // xlds now holds x3; hbuf (actlds) free

  f32x4 dacc[4][4];
  #pragma unroll
  for (int rt = 0; rt < 4; ++rt)
    #pragma unroll
    for (int st = 0; st < 4; ++st) dacc[rt][st] = (f32x4)0.f;

  for (int chunk = 0; chunk < 8; ++chunk) {
    const int nc = (chunk + 1) & 7;

    // ---- GEMM1(chunk)
    f32x4 hacc[2][4];
    #pragma unroll
    for (int ntl = 0; ntl < 2; ++ntl)
      #pragma unroll
      for (int st = 0; st < 4; ++st) hacc[ntl][st] = (f32x4)0.f;

    #pragma unroll
    for (int ks = 0; ks < 8; ++ks) {
      bf16x8 bfr[4];
      #pragma unroll
      for (int st = 0; st < 4; ++st)
        bfr[st] = *(const bf16x8*)&xlds[st * 16 + lrow][(((ks * 4 + lgrp) ^ swz)) << 3];
      #pragma unroll
      for (int ntl = 0; ntl < 2; ++ntl)
        #pragma unroll
        for (int st = 0; st < 4; ++st)
          hacc[ntl][st] = __builtin_amdgcn_mfma_f32_16x16x32_bf16(
              a1[ntl][ks], bfr[st], hacc[ntl][st], 0, 0, 0);
    }

    // ---- prefetch a1 for next chunk
    #pragma unroll
    for (int ntl = 0; ntl < 2; ++ntl)
      #pragma unroll
      for (int ks = 0; ks < 8; ++ks)
        a1[ntl][ks] = b1f[((nc * 8 + wave * 2 + ntl) * 8 + ks) * 64 + lane];

    // ---- bias + gelu -> act[chunk&1]
    uint* act32 = (uint*)&actlds[chunk & 1][0][0];
    #pragma unroll
    for (int ntl = 0; ntl < 2; ++ntl) {
      const int nlocal0 = (wave * 2 + ntl) * 16 + lgrp * 4;
      const int ng0 = chunk * 128 + nlocal0;
      #pragma unroll
      for (int st = 0; st < 4; ++st) {
        float gv[4];
        #pragma unroll
        for (int j = 0; j < 4; ++j) {
          const int ng = ng0 + j;
          const float bias = (ng < 512) ? b1_re[ng] : b1_im[ng - 512];
          gv[j] = gelu_fast(hacc[ntl][st][j] + bias);
        }
        const int site = st * 16 + lrow;
        act32[site * 68 + (nlocal0 >> 1)] = cvt_pk(gv[0], gv[1]);
        act32[site * 68 + (nlocal0 >> 1) + 1] = cvt_pk(gv[2], gv[3]);
      }
    }

    // ---- load this chunk's GEMM2 ks2 2-3 frags
    bf16x8 a2b[4][2];
    #pragma unroll
    for (int rt = 0; rt < 4; ++rt)
      #pragma unroll
      for (int k2 = 0; k2 < 2; ++k2)
        a2b[rt][k2] = b2f[((wave * 4 + rt) * 32 + chunk * 4 + 2 + k2) * 64 + lane];

    __syncthreads();   // act[chunk&1] ready (one barrier/chunk)

    // ---- GEMM2(chunk)
    const ushort* actb = &actlds[chunk & 1][0][0];
    #pragma unroll
    for (int ks2 = 0; ks2 < 2; ++ks2) {
      bf16x8 bfr[4];
      #pragma unroll
      for (int st = 0; st < 4; ++st)
        bfr[st] = *(const bf16x8*)&actb[(st * 16 + lrow) * 136 + ks2 * 32 + lgrp * 8];
      #pragma unroll
      for (int rt = 0; rt < 4; ++rt)
        #pragma unroll
        for (int st = 0; st < 4; ++st)
          dacc[rt][st] = __builtin_amdgcn_mfma_f32_16x16x32_bf16(
              a2[rt][ks2], bfr[st], dacc[rt][st], 0, 0, 0);
    }
    #pragma unroll
    for (int ks2 = 0; ks2 < 2; ++ks2) {
      bf16x8 bfr[4];
      #pragma unroll
      for (int st = 0; st < 4; ++st)
        bfr[st] = *(const bf16x8*)&actb[(st * 16 + lrow) * 136 + (ks2 + 2) * 32 + lgrp * 8];
      #pragma unroll
      for (int rt = 0; rt < 4; ++rt)
        #pragma unroll
        for (int st = 0; st < 4; ++st)
          dacc[rt][st] = __builtin_amdgcn_mfma_f32_16x16x32_bf16(
              a2b[rt][ks2], bfr[st], dacc[rt][st], 0, 0, 0);
    }

    // ---- prefetch next chunk's GEMM2 ks2 0-1 frags
    #pragma unroll
    for (int rt = 0; rt < 4; ++rt)
      #pragma unroll
      for (int k2 = 0; k2 < 2; ++k2)
        a2[rt][k2] = b2f[((wave * 4 + rt) * 32 + nc * 4 + k2) * 64 + lane];
  }

  // epilogue: residual x3 from xlds, bias2, interleaved [.,2] output
  #pragma unroll
  for (int rt = 0; rt < 4; ++rt) {
    #pragma unroll
    for (int j = 0; j < 4; ++j) {
      const int n2 = (wave * 4 + rt) * 16 + lgrp * 4 + j;
      const int d = n2 & 127;
      const int c = n2 >> 7;
      const float bias2 = c ? b2_im[d] : b2_re[d];
      #pragma unroll
      for (int st = 0; st < 4; ++st) {
        const int site = st * 16 + lrow;
        const uint pr = *(const uint*)&xlds[site][(((d >> 2) ^ (site & 7)) << 3)
                                                  + (d & 3) * 2];
        const float rv = c ? __uint_as_float(pr & 0xffff0000u)
                           : __uint_as_float(pr << 16);
        const size_t idx = (size_t)(bt * D_ + d) * HW_ + hw0 + site;
        out[idx * 2 + c] = rv + dacc[rt][st][j] + bias2;
      }
    }
  }
}

// ---------------- host launcher ----------------

extern "C" void kernel_launch(void* const* d_in, const int* in_sizes, int n_in,
                              void* d_out, int out_size, void* d_ws, size_t ws_size,
                              hipStream_t stream) {
  const float* x_re   = (const float*)d_in[0];
  const float* x_im   = (const float*)d_in[1];
  const float* dt     = (const float*)d_in[2];
  const float* ln_s_g = (const float*)d_in[3];
  const float* ln_s_b = (const float*)d_in[4];
  const float* ln_t_g = (const float*)d_in[5];
  const float* ln_t_b = (const float*)d_in[6];
  const float* metric = (const float*)d_in[7];
  const float* conv_w = (const float*)d_in[8];
  const float* conv_b = (const float*)d_in[9];
  const float* nu     = (const float*)d_in[10];
  const float* theta  = (const float*)d_in[11];
  const float* enc_re = (const float*)d_in[12];
  const float* enc_im = (const float*)d_in[13];
  const float* dec_re = (const float*)d_in[14];
  const float* dec_im = (const float*)d_in[15];
  const float* src_g  = (const float*)d_in[16];
  const float* w1_re  = (const float*)d_in[17];
  const float* w1_im  = (const float*)d_in[18];
  const float* b1_re  = (const float*)d_in[19];
  const float* b1_im  = (const float*)d_in[20];
  const float* w2_re  = (const float*)d_in[21];
  const float* w2_im  = (const float*)d_in[22];
  const float* b2_re  = (const float*)d_in[23];
  const float* b2_im  = (const float*)d_in[24];
  float* out = (float*)d_out;
  float* ws = (float*)d_ws;

  // prep region (non-aliased: all weights prepped once, up front)
  ushort* wt16   = (ushort*)ws;
  ushort* cwswz  = wt16;                     // 589,824 ushorts
  ushort* b1swz  = wt16 + 589824;            // 262,144
  ushort* b2swz  = wt16 + 851968;            // 262,144
  ushort* encswz = wt16 + 1114112;           // 65,536
  ushort* decswz = wt16 + 1179648;           // 32,768
  float*  evec   = (float*)(wt16 + 1212416); // 256
  float*  cvec   = evec + 256;               // 256
  float4* decay  = (float4*)(cvec + 256);    // 4096 float4 (64 KB)
  float*  bufA   = ws + PREP_FLOATS;
  ushort* xri_bf = (ushort*)bufA;            // 67 MB (dead after conv)

  // planA: xri | u32(+128KB skew over xri) | x2p(+256KB skew) | xp(+512KB skew)
  const size_t needA = ((size_t)PREP_FLOATS + 3 * (size_t)PLANE_) * 4 + (2u << 20);
  const bool planA = ws_size >= needA;
  uint *u32p, *x2p, *xp;
  float* ffn_out;
  if (planA) {
    u32p = (uint*)bufA + 32768;                      // overwrites dead xri (skewed)
    x2p  = (uint*)bufA + PLANE_ + 65536;
    xp   = (uint*)bufA + 2 * (size_t)PLANE_ + 131072;
    ffn_out = out;
  } else {
    // route u32/x2p through d_out; xp in ws after xri; final d2d copy
    u32p = (uint*)out;
    x2p  = (uint*)out + PLANE_;
    xp   = (uint*)bufA + PLANE_;
    ffn_out = bufA;
  }

  k_prep_all<<<609, 256, 0, stream>>>(conv_w, dt, nu, theta, w1_re, w1_im,
                                      w2_re, w2_im, enc_re, enc_im, dec_re, dec_im,
                                      ln_t_g, ln_t_b,
                                      cwswz, decay, b1swz, b2swz, encswz, decswz,
                                      evec, cvec);
  k_spatial_ln<<<BT_ * H_, 256, 0, stream>>>(x_re, x_im, ln_s_g, ln_s_b, metric,
                                             xri_bf, xp);
  k_conv_mfma<<<BT_ * 32, 512, 0, stream>>>(xri_bf, cwswz, conv_b, xp, x2p);
  k_temporal_mfma<<<B_ * T_ * H_, 256, 0, stream>>>(x2p, encswz, evec, cvec,
                                                    decay, src_g, u32p);
  k_scan<<<ND_ / 512, 256, 0, stream>>>((uint2*)u32p, decay);
  k_ffn_mfma<<<BT_ * H_, 256, 0, stream>>>(x2p, u32p, decswz, b1swz, b2swz,
                                           b1_re, b1_im, b2_re, b2_im, ffn_out);
  if (!planA) {
    hipMemcpyAsync(d_out, ffn_out, (size_t)2 * PLANE_ * sizeof(float),
                   hipMemcpyDeviceToDevice, stream);
  }
}